// Round 6
// baseline (513.434 us; speedup 1.0000x reference)
//
#include <hip/hip_runtime.h>
#include <hip/hip_bf16.h>
#include <math.h>

#define N_NODES_C 100000
#define N_EDGES_C 1600000
#define N_GRAPHS_C 512
#define SCAN_CHUNK 1024   // elements per scan block
#define SCAN_NB ((N_NODES_C + SCAN_CHUNK) / SCAN_CHUNK + 1)  // generous

__device__ __forceinline__ float elu_f(float x) { return x > 0.f ? x : expm1f(x); }

__device__ __forceinline__ int wave_incl_scan(int v) {
    int lane = threadIdx.x & 63;
#pragma unroll
    for (int o = 1; o < 64; o <<= 1) {
        int t = __shfl_up(v, o);
        if (lane >= o) v += t;
    }
    return v;
}

__device__ __forceinline__ int wave_sum_i(int v) {
#pragma unroll
    for (int o = 32; o > 0; o >>= 1) v += __shfl_xor(v, o);
    return v;
}

// ---------------------------------------------------------------------------
// CSR build: histogram of in-degrees, exclusive scan, positioned fill.
// ---------------------------------------------------------------------------
__global__ __launch_bounds__(256) void hist_kernel(
    const int* __restrict__ dst, int* __restrict__ deg, int nE)
{
    int e = blockIdx.x * 256 + threadIdx.x;
    if (e < nE) atomicAdd(&deg[dst[e]], 1);
}

__global__ __launch_bounds__(256) void scan_pass1(
    const int* __restrict__ deg, int* __restrict__ bsum, int n)
{
    int base = blockIdx.x * SCAN_CHUNK;
    int s = 0;
    for (int i = threadIdx.x; i < SCAN_CHUNK; i += 256) {
        int idx = base + i;
        if (idx < n) s += deg[idx];
    }
    s = wave_sum_i(s);
    __shared__ int ws[4];
    int lane = threadIdx.x & 63, w = threadIdx.x >> 6;
    if (lane == 0) ws[w] = s;
    __syncthreads();
    if (threadIdx.x == 0) bsum[blockIdx.x] = ws[0] + ws[1] + ws[2] + ws[3];
}

__global__ __launch_bounds__(128) void scan_pass2(int* __restrict__ bsum, int nb)
{
    int tid = threadIdx.x;  // 128 threads, nb <= 128
    int v = tid < nb ? bsum[tid] : 0;
    int lane = tid & 63, w = tid >> 6;
    int incl = wave_incl_scan(v);
    __shared__ int ws[2];
    if (lane == 63) ws[w] = incl;
    __syncthreads();
    int off = (w == 1) ? ws[0] : 0;
    if (tid < nb) bsum[tid] = off + incl - v;  // exclusive
}

__global__ __launch_bounds__(256) void scan_pass3(
    const int* __restrict__ deg, const int* __restrict__ bsum,
    int* __restrict__ row_start, int* __restrict__ pos, int n)
{
    int base = blockIdx.x * SCAN_CHUNK + threadIdx.x * 4;
    int v[4];
#pragma unroll
    for (int k = 0; k < 4; ++k) {
        int idx = base + k;
        v[k] = (idx < n) ? deg[idx] : 0;
    }
    int lsum = v[0] + v[1] + v[2] + v[3];
    int incl = wave_incl_scan(lsum);
    __shared__ int ws[4];
    int lane = threadIdx.x & 63, w = threadIdx.x >> 6;
    if (lane == 63) ws[w] = incl;
    __syncthreads();
    int woff = 0;
    for (int i = 0; i < w; ++i) woff += ws[i];
    int p = bsum[blockIdx.x] + woff + incl - lsum;  // exclusive base
#pragma unroll
    for (int k = 0; k < 4; ++k) {
        int idx = base + k;
        if (idx <= n) row_start[idx] = p;
        if (idx < n)  pos[idx] = p;
        p += v[k];
    }
}

__global__ __launch_bounds__(256) void fill_kernel(
    const int* __restrict__ src, const int* __restrict__ dst,
    int* __restrict__ pos, int* __restrict__ ssrc, int nE)
{
    int e = blockIdx.x * 256 + threadIdx.x;
    if (e < nE) {
        int p = atomicAdd(&pos[dst[e]], 1);
        __builtin_nontemporal_store(src[e], &ssrc[p]);
    }
}

// ---------------------------------------------------------------------------
// Fused layer: gather-sum (CSR) into LDS + node transform, one kernel.
//   phase 1: a_s[node] = sum_j x[ssrc[e]], x_s[node] = x[node]  (LDS)
//   phase 2: out[n] = ELU( a_s[n]@w_rel + x_s[n]@w_root + b )
// No global intermediate. k-loop rolled (#pragma unroll 2) — full unroll
// spilled at 256 VGPRs in v2/v3.
// ---------------------------------------------------------------------------
template<int DIN, int DOUT>
__global__ __launch_bounds__(256) void fused_layer(
    const float* __restrict__ xin, const int* __restrict__ row_start,
    const int* __restrict__ ssrc,
    const float* __restrict__ w_rel, const float* __restrict__ bias,
    const float* __restrict__ w_root, float* __restrict__ out, int nNodes)
{
    constexpr int JB = 8;               // outputs per thread
    constexpr int TPN = DOUT / JB;      // threads per node (transform)
    constexpr int NPB = 256 / TPN;      // nodes per block
    constexpr int PITCH = DIN + 4;      // padded rows
    constexpr int CH = DIN / 4;         // float4 chunks per row

    __shared__ float wr[DIN * DOUT];
    __shared__ float wt[DIN * DOUT];
    __shared__ float a_s[NPB * PITCH];
    __shared__ float x_s[NPB * PITCH];

    // weights -> LDS
    {
        const float4* wr4 = reinterpret_cast<const float4*>(w_rel);
        const float4* wt4 = reinterpret_cast<const float4*>(w_root);
        float4* wrd = reinterpret_cast<float4*>(wr);
        float4* wtd = reinterpret_cast<float4*>(wt);
        for (int i = threadIdx.x; i < DIN * DOUT / 4; i += 256) {
            wrd[i] = wr4[i];
            wtd[i] = wt4[i];
        }
    }

    int n0 = blockIdx.x * NPB;

    // phase 1: gather neighbors + own row into LDS
    constexpr int ITEMS = NPB * CH;
    for (int it = threadIdx.x; it < ITEMS; it += 256) {
        int row = it / CH;
        int c   = it % CH;
        int n = n0 + row;
        float4 acc = make_float4(0.f, 0.f, 0.f, 0.f);
        float4 xx  = acc;
        if (n < nNodes) {
            xx = *reinterpret_cast<const float4*>(xin + (size_t)n * DIN + c * 4);
            int beg = row_start[n], end = row_start[n + 1];
            int e = beg;
            for (; e + 1 < end; e += 2) {
                int s0 = ssrc[e], s1 = ssrc[e + 1];
                float4 v0 = *reinterpret_cast<const float4*>(xin + (size_t)s0 * DIN + c * 4);
                float4 v1 = *reinterpret_cast<const float4*>(xin + (size_t)s1 * DIN + c * 4);
                acc.x += v0.x + v1.x; acc.y += v0.y + v1.y;
                acc.z += v0.z + v1.z; acc.w += v0.w + v1.w;
            }
            if (e < end) {
                int s0 = ssrc[e];
                float4 v0 = *reinterpret_cast<const float4*>(xin + (size_t)s0 * DIN + c * 4);
                acc.x += v0.x; acc.y += v0.y; acc.z += v0.z; acc.w += v0.w;
            }
        }
        *reinterpret_cast<float4*>(&a_s[row * PITCH + c * 4]) = acc;
        *reinterpret_cast<float4*>(&x_s[row * PITCH + c * 4]) = xx;
    }
    __syncthreads();

    // phase 2: transform
    int slot = threadIdx.x / TPN;
    int j0 = (threadIdx.x % TPN) * JB;

    float4 acc0 = *reinterpret_cast<const float4*>(bias + j0);
    float4 acc1 = *reinterpret_cast<const float4*>(bias + j0 + 4);

    const float* ar = &a_s[slot * PITCH];
    const float* xr = &x_s[slot * PITCH];

#pragma unroll 2
    for (int k = 0; k < DIN; ++k) {
        float av = ar[k], xv = xr[k];
        float4 w0 = *reinterpret_cast<const float4*>(&wr[k * DOUT + j0]);
        float4 w1 = *reinterpret_cast<const float4*>(&wr[k * DOUT + j0 + 4]);
        float4 t0 = *reinterpret_cast<const float4*>(&wt[k * DOUT + j0]);
        float4 t1 = *reinterpret_cast<const float4*>(&wt[k * DOUT + j0 + 4]);
        acc0.x += av * w0.x + xv * t0.x;
        acc0.y += av * w0.y + xv * t0.y;
        acc0.z += av * w0.z + xv * t0.z;
        acc0.w += av * w0.w + xv * t0.w;
        acc1.x += av * w1.x + xv * t1.x;
        acc1.y += av * w1.y + xv * t1.y;
        acc1.z += av * w1.z + xv * t1.z;
        acc1.w += av * w1.w + xv * t1.w;
    }

    int n = n0 + slot;
    if (n < nNodes) {
        float4 o0, o1;
        o0.x = elu_f(acc0.x); o0.y = elu_f(acc0.y); o0.z = elu_f(acc0.z); o0.w = elu_f(acc0.w);
        o1.x = elu_f(acc1.x); o1.y = elu_f(acc1.y); o1.z = elu_f(acc1.z); o1.w = elu_f(acc1.w);
        *reinterpret_cast<float4*>(out + (size_t)n * DOUT + j0)     = o0;
        *reinterpret_cast<float4*>(out + (size_t)n * DOUT + j0 + 4) = o1;
    }
}

// ---------------------------------------------------------------------------
// Mean-pool over sorted `batch`.
// ---------------------------------------------------------------------------
#define POOL_CHUNK 256
__global__ __launch_bounds__(64) void pool_kernel(
    const float* __restrict__ h, const int* __restrict__ batch,
    float* __restrict__ sums, float* __restrict__ cnts, int nNodes)
{
    int j = threadIdx.x;
    int start = blockIdx.x * POOL_CHUNK;
    int end = start + POOL_CHUNK;
    if (end > nNodes) end = nNodes;
    if (start >= end) return;

    int g = batch[start];
    float acc = 0.f;
    float c = 0.f;
    for (int n = start; n < end; ++n) {
        int gn = batch[n];
        if (gn != g) {
            unsafeAtomicAdd(&sums[(size_t)g * 64 + j], acc);
            if (j == 0) unsafeAtomicAdd(&cnts[g], c);
            acc = 0.f; c = 0.f; g = gn;
        }
        acc += h[(size_t)n * 64 + j];
        c += 1.f;
    }
    unsafeAtomicAdd(&sums[(size_t)g * 64 + j], acc);
    if (j == 0) unsafeAtomicAdd(&cnts[g], c);
}

// ---------------------------------------------------------------------------
// MLP head + log_softmax: one 64-thread block per graph.
// ---------------------------------------------------------------------------
__global__ __launch_bounds__(64) void mlp_kernel(
    const float* __restrict__ sums, const float* __restrict__ cnts,
    const float* __restrict__ fw1, const float* __restrict__ fb1,
    const float* __restrict__ fw2, const float* __restrict__ fb2,
    const float* __restrict__ fw3, const float* __restrict__ fb3,
    float* __restrict__ out)
{
    int g = blockIdx.x;
    int j = threadIdx.x;
    __shared__ float p[64];
    __shared__ float z1[64];
    __shared__ float z2[32];
    __shared__ float z3[10];
    __shared__ float lse;

    float c = fmaxf(cnts[g], 1.f);
    p[j] = sums[(size_t)g * 64 + j] / c;
    __syncthreads();

    float a = fb1[j];
#pragma unroll
    for (int k = 0; k < 64; ++k) a += p[k] * fw1[k * 64 + j];
    z1[j] = elu_f(a);
    __syncthreads();

    if (j < 32) {
        float a2 = fb2[j];
#pragma unroll
        for (int k = 0; k < 64; ++k) a2 += z1[k] * fw2[k * 32 + j];
        z2[j] = elu_f(a2);
    }
    __syncthreads();

    if (j < 10) {
        float a3 = fb3[j];
#pragma unroll
        for (int k = 0; k < 32; ++k) a3 += z2[k] * fw3[k * 10 + j];
        z3[j] = a3;
    }
    __syncthreads();

    if (j == 0) {
        float m = -1e30f;
        for (int i = 0; i < 10; ++i) m = fmaxf(m, z3[i]);
        float s = 0.f;
        for (int i = 0; i < 10; ++i) s += expf(z3[i] - m);
        lse = logf(s) + m;
    }
    __syncthreads();

    if (j < 10) out[(size_t)g * 10 + j] = z3[j] - lse;
}

// ---------------------------------------------------------------------------
extern "C" void kernel_launch(void* const* d_in, const int* in_sizes, int n_in,
                              void* d_out, int out_size, void* d_ws, size_t ws_size,
                              hipStream_t stream)
{
    const float* x       = (const float*)d_in[0];
    const int*   ei      = (const int*)  d_in[1];
    const int*   batch   = (const int*)  d_in[2];
    const float* w1_rel  = (const float*)d_in[3];
    const float* b1      = (const float*)d_in[4];
    const float* w1_root = (const float*)d_in[5];
    const float* w2_rel  = (const float*)d_in[6];
    const float* b2      = (const float*)d_in[7];
    const float* w2_root = (const float*)d_in[8];
    const float* w3_rel  = (const float*)d_in[9];
    const float* b3      = (const float*)d_in[10];
    const float* w3_root = (const float*)d_in[11];
    const float* fw1     = (const float*)d_in[12];
    const float* fb1     = (const float*)d_in[13];
    const float* fw2     = (const float*)d_in[14];
    const float* fb2     = (const float*)d_in[15];
    const float* fw3     = (const float*)d_in[16];
    const float* fb3     = (const float*)d_in[17];
    float* out = (float*)d_out;

    const int* src = ei;
    const int* dst = ei + N_EDGES_C;

    // workspace layout
    float* hB   = (float*)d_ws;                          // N*64 f
    float* hC   = hB   + (size_t)N_NODES_C * 64;         // N*64 f
    float* sums = hC   + (size_t)N_NODES_C * 64;         // 512*64 f
    float* cnts = sums + (size_t)N_GRAPHS_C * 64;        // 512 f
    int*   deg  = (int*)(cnts + N_GRAPHS_C);             // N int
    int*   row_start = deg + N_NODES_C;                  // N+1 int
    int*   pos  = row_start + N_NODES_C + 1;             // N int
    int*   bsum = pos + N_NODES_C;                       // SCAN_NB int
    int*   ssrc = bsum + SCAN_NB;                        // nE int

    const int nb = (N_NODES_C + SCAN_CHUNK - 1) / SCAN_CHUNK;  // 98

    // ---- CSR build (once, reused by all 3 layers) ----
    hipMemsetAsync(deg, 0, (size_t)N_NODES_C * sizeof(int), stream);
    hist_kernel<<<(N_EDGES_C + 255) / 256, 256, 0, stream>>>(dst, deg, N_EDGES_C);
    scan_pass1<<<nb, 256, 0, stream>>>(deg, bsum, N_NODES_C);
    scan_pass2<<<1, 128, 0, stream>>>(bsum, nb);
    scan_pass3<<<nb, 256, 0, stream>>>(deg, bsum, row_start, pos, N_NODES_C);
    fill_kernel<<<(N_EDGES_C + 255) / 256, 256, 0, stream>>>(src, dst, pos, ssrc, N_EDGES_C);

    // ---- layer 1: 32 -> 32, x -> hB ----  (NPB=64)
    fused_layer<32, 32><<<(N_NODES_C + 63) / 64, 256, 0, stream>>>(
        x, row_start, ssrc, w1_rel, b1, w1_root, hB, N_NODES_C);

    // ---- layer 2: 32 -> 64, hB -> hC ----  (NPB=32)
    fused_layer<32, 64><<<(N_NODES_C + 31) / 32, 256, 0, stream>>>(
        hB, row_start, ssrc, w2_rel, b2, w2_root, hC, N_NODES_C);

    // ---- layer 3: 64 -> 64, hC -> hB ----  (NPB=32)
    fused_layer<64, 64><<<(N_NODES_C + 31) / 32, 256, 0, stream>>>(
        hC, row_start, ssrc, w3_rel, b3, w3_root, hB, N_NODES_C);

    // ---- mean pool ----
    hipMemsetAsync(sums, 0, ((size_t)N_GRAPHS_C * 64 + N_GRAPHS_C) * sizeof(float), stream);
    pool_kernel<<<(N_NODES_C + POOL_CHUNK - 1) / POOL_CHUNK, 64, 0, stream>>>(
        hB, batch, sums, cnts, N_NODES_C);

    // ---- MLP head + log_softmax ----
    mlp_kernel<<<N_GRAPHS_C, 64, 0, stream>>>(
        sums, cnts, fw1, fb1, fw2, fb2, fw3, fb3, out);
}

// Round 7
// 420.786 us; speedup vs baseline: 1.2202x; 1.2202x over previous
//
#include <hip/hip_runtime.h>
#include <hip/hip_bf16.h>
#include <math.h>

#define N_NODES_C 100000
#define N_EDGES_C 1600000
#define N_GRAPHS_C 512
#define SCAN_CHUNK 1024
#define SCAN_NB ((N_NODES_C + SCAN_CHUNK) / SCAN_CHUNK + 1)
#define BSHIFT 10
#define NBUCK ((N_NODES_C + (1 << BSHIFT) - 1) >> BSHIFT)   // 98
#define CHUNK_A 8192

__device__ __forceinline__ float elu_f(float x) { return x > 0.f ? x : expm1f(x); }

__device__ __forceinline__ int wave_incl_scan(int v) {
    int lane = threadIdx.x & 63;
#pragma unroll
    for (int o = 1; o < 64; o <<= 1) {
        int t = __shfl_up(v, o);
        if (lane >= o) v += t;
    }
    return v;
}

__device__ __forceinline__ int wave_sum_i(int v) {
#pragma unroll
    for (int o = 32; o > 0; o >>= 1) v += __shfl_xor(v, o);
    return v;
}

// ---------------------------------------------------------------------------
// CSR build: histogram of in-degrees + exclusive scan -> row_start.
// ---------------------------------------------------------------------------
__global__ __launch_bounds__(256) void hist_kernel(
    const int* __restrict__ dst, int* __restrict__ deg, int nE)
{
    int e = blockIdx.x * 256 + threadIdx.x;
    if (e < nE) atomicAdd(&deg[dst[e]], 1);
}

__global__ __launch_bounds__(256) void scan_pass1(
    const int* __restrict__ deg, int* __restrict__ bsum, int n)
{
    int base = blockIdx.x * SCAN_CHUNK;
    int s = 0;
    for (int i = threadIdx.x; i < SCAN_CHUNK; i += 256) {
        int idx = base + i;
        if (idx < n) s += deg[idx];
    }
    s = wave_sum_i(s);
    __shared__ int ws[4];
    int lane = threadIdx.x & 63, w = threadIdx.x >> 6;
    if (lane == 0) ws[w] = s;
    __syncthreads();
    if (threadIdx.x == 0) bsum[blockIdx.x] = ws[0] + ws[1] + ws[2] + ws[3];
}

__global__ __launch_bounds__(128) void scan_pass2(int* __restrict__ bsum, int nb)
{
    int tid = threadIdx.x;
    int v = tid < nb ? bsum[tid] : 0;
    int lane = tid & 63, w = tid >> 6;
    int incl = wave_incl_scan(v);
    __shared__ int ws[2];
    if (lane == 63) ws[w] = incl;
    __syncthreads();
    int off = (w == 1) ? ws[0] : 0;
    if (tid < nb) bsum[tid] = off + incl - v;  // exclusive
}

__global__ __launch_bounds__(256) void scan_pass3(
    const int* __restrict__ deg, const int* __restrict__ bsum,
    int* __restrict__ row_start, int n)
{
    int base = blockIdx.x * SCAN_CHUNK + threadIdx.x * 4;
    int v[4];
#pragma unroll
    for (int k = 0; k < 4; ++k) {
        int idx = base + k;
        v[k] = (idx < n) ? deg[idx] : 0;
    }
    int lsum = v[0] + v[1] + v[2] + v[3];
    int incl = wave_incl_scan(lsum);
    __shared__ int ws[4];
    int lane = threadIdx.x & 63, w = threadIdx.x >> 6;
    if (lane == 63) ws[w] = incl;
    __syncthreads();
    int woff = 0;
    for (int i = 0; i < w; ++i) woff += ws[i];
    int p = bsum[blockIdx.x] + woff + incl - lsum;
#pragma unroll
    for (int k = 0; k < 4; ++k) {
        int idx = base + k;
        if (idx <= n) row_start[idx] = p;
        p += v[k];
    }
}

// ---------------------------------------------------------------------------
// Bucketed edge sort (replaces random-write fill_kernel):
//   cursor[b] starts at row_start[b<<BSHIFT]; pass A partitions edges into
//   per-bucket contiguous regions of ebuf; pass B does the exact positioned
//   fill with the bucket's pos cursors in LDS and writes confined to the
//   bucket's contiguous ssrc window (full-line writebacks).
// ---------------------------------------------------------------------------
__global__ __launch_bounds__(64) void cursor_init(
    const int* __restrict__ row_start, int* __restrict__ cursor)
{
    int b = blockIdx.x * 64 + threadIdx.x;
    if (b < NBUCK) {
        int n = b << BSHIFT;
        if (n > N_NODES_C) n = N_NODES_C;
        cursor[b] = row_start[n];
    }
}

__global__ __launch_bounds__(256) void bucket_pass(
    const int* __restrict__ src, const int* __restrict__ dst,
    int* __restrict__ cursor, int2* __restrict__ ebuf, int nE)
{
    __shared__ int cnt[NBUCK];
    __shared__ int base[NBUCK];
    int t = threadIdx.x;
    for (int i = t; i < NBUCK; i += 256) cnt[i] = 0;
    __syncthreads();

    int lo = blockIdx.x * CHUNK_A;
    int hi = lo + CHUNK_A;
    if (hi > nE) hi = nE;

    for (int e = lo + t; e < hi; e += 256)
        atomicAdd(&cnt[dst[e] >> BSHIFT], 1);
    __syncthreads();

    for (int i = t; i < NBUCK; i += 256)
        base[i] = cnt[i] ? atomicAdd(&cursor[i], cnt[i]) : 0;
    __syncthreads();
    for (int i = t; i < NBUCK; i += 256) cnt[i] = 0;
    __syncthreads();

    for (int e = lo + t; e < hi; e += 256) {
        int d = dst[e];
        int b = d >> BSHIFT;
        int p = base[b] + atomicAdd(&cnt[b], 1);
        ebuf[p] = make_int2(src[e], d);
    }
}

__global__ __launch_bounds__(256) void bucket_fill(
    const int* __restrict__ row_start, const int2* __restrict__ ebuf,
    int* __restrict__ ssrc)
{
    int b = blockIdx.x;
    int nlo = b << BSHIFT;
    int nhi = nlo + (1 << BSHIFT);
    if (nhi > N_NODES_C) nhi = N_NODES_C;

    __shared__ int pos_l[1 << BSHIFT];
    int t = threadIdx.x;
    for (int i = t; i < nhi - nlo; i += 256) pos_l[i] = row_start[nlo + i];
    __syncthreads();

    int lo = row_start[nlo];
    int hi = row_start[nhi];
    for (int e = lo + t; e < hi; e += 256) {
        int2 sd = ebuf[e];
        int p = atomicAdd(&pos_l[sd.y - nlo], 1);
        ssrc[p] = sd.x;
    }
}

// ---------------------------------------------------------------------------
// Gather-sum aggregation (round-5 measured version).
// ---------------------------------------------------------------------------
template<int D>
__global__ __launch_bounds__(256) void gather_agg(
    const float* __restrict__ x, const int* __restrict__ row_start,
    const int* __restrict__ ssrc, float* __restrict__ agg, int nNodes)
{
    const int L = D / 4;
    const int NPB = 256 / L;
    int local = threadIdx.x / L;
    int lane  = threadIdx.x % L;
    int n = blockIdx.x * NPB + local;
    if (n >= nNodes) return;
    int beg = row_start[n], end = row_start[n + 1];
    float4 acc = make_float4(0.f, 0.f, 0.f, 0.f);
    int e = beg;
    for (; e + 1 < end; e += 2) {
        int s0 = ssrc[e], s1 = ssrc[e + 1];
        float4 v0 = *reinterpret_cast<const float4*>(x + (size_t)s0 * D + lane * 4);
        float4 v1 = *reinterpret_cast<const float4*>(x + (size_t)s1 * D + lane * 4);
        acc.x += v0.x + v1.x; acc.y += v0.y + v1.y;
        acc.z += v0.z + v1.z; acc.w += v0.w + v1.w;
    }
    if (e < end) {
        int s0 = ssrc[e];
        float4 v0 = *reinterpret_cast<const float4*>(x + (size_t)s0 * D + lane * 4);
        acc.x += v0.x; acc.y += v0.y; acc.z += v0.z; acc.w += v0.w;
    }
    *reinterpret_cast<float4*>(agg + (size_t)n * D + lane * 4) = acc;
}

// ---------------------------------------------------------------------------
// Node transform v4 (round-5 measured version): LDS-staged inputs,
// 2 nodes x 8 outputs per thread, rolled k-loop (full unroll spilled).
// ---------------------------------------------------------------------------
template<int DIN, int DOUT>
__global__ __launch_bounds__(256) void transform_v4(
    const float* __restrict__ agg, const float* __restrict__ xin,
    const float* __restrict__ w_rel, const float* __restrict__ bias,
    const float* __restrict__ w_root, float* __restrict__ out, int nNodes)
{
    constexpr int JB = 8;
    constexpr int TPN = DOUT / JB;
    constexpr int SLOTS = 256 / TPN;
    constexpr int NT = 2;
    constexpr int NPB = SLOTS * NT;
    constexpr int PITCH = DIN + 4;

    __shared__ float wr[DIN * DOUT];
    __shared__ float wt[DIN * DOUT];
    __shared__ float a_s[NPB * PITCH];
    __shared__ float x_s[NPB * PITCH];

    {
        const float4* wr4 = reinterpret_cast<const float4*>(w_rel);
        const float4* wt4 = reinterpret_cast<const float4*>(w_root);
        float4* wrd = reinterpret_cast<float4*>(wr);
        float4* wtd = reinterpret_cast<float4*>(wt);
        for (int i = threadIdx.x; i < DIN * DOUT / 4; i += 256) {
            wrd[i] = wr4[i];
            wtd[i] = wt4[i];
        }
    }

    int n0 = blockIdx.x * NPB;
    constexpr int NV = NPB * DIN / 4;
    for (int v = threadIdx.x; v < NV; v += 256) {
        int row  = v / (DIN / 4);
        int col4 = v % (DIN / 4);
        int n = n0 + row;
        float4 a = make_float4(0.f, 0.f, 0.f, 0.f);
        float4 xx = a;
        if (n < nNodes) {
            a  = *reinterpret_cast<const float4*>(agg + (size_t)n * DIN + col4 * 4);
            xx = *reinterpret_cast<const float4*>(xin + (size_t)n * DIN + col4 * 4);
        }
        *reinterpret_cast<float4*>(&a_s[row * PITCH + col4 * 4]) = a;
        *reinterpret_cast<float4*>(&x_s[row * PITCH + col4 * 4]) = xx;
    }
    __syncthreads();

    int slot = threadIdx.x / TPN;
    int j0 = (threadIdx.x % TPN) * JB;

    float4 biasLo = *reinterpret_cast<const float4*>(bias + j0);
    float4 biasHi = *reinterpret_cast<const float4*>(bias + j0 + 4);
    float4 accA0 = biasLo, accA1 = biasHi;
    float4 accB0 = biasLo, accB1 = biasHi;

    const float* arA = &a_s[slot * PITCH];
    const float* xrA = &x_s[slot * PITCH];
    const float* arB = arA + SLOTS * PITCH;
    const float* xrB = xrA + SLOTS * PITCH;

#pragma unroll 2
    for (int k = 0; k < DIN; ++k) {
        float aA = arA[k], xA = xrA[k];
        float aB = arB[k], xB = xrB[k];
        float4 w0 = *reinterpret_cast<const float4*>(&wr[k * DOUT + j0]);
        float4 w1 = *reinterpret_cast<const float4*>(&wr[k * DOUT + j0 + 4]);
        float4 t0 = *reinterpret_cast<const float4*>(&wt[k * DOUT + j0]);
        float4 t1 = *reinterpret_cast<const float4*>(&wt[k * DOUT + j0 + 4]);
        accA0.x += aA * w0.x + xA * t0.x;
        accA0.y += aA * w0.y + xA * t0.y;
        accA0.z += aA * w0.z + xA * t0.z;
        accA0.w += aA * w0.w + xA * t0.w;
        accA1.x += aA * w1.x + xA * t1.x;
        accA1.y += aA * w1.y + xA * t1.y;
        accA1.z += aA * w1.z + xA * t1.z;
        accA1.w += aA * w1.w + xA * t1.w;
        accB0.x += aB * w0.x + xB * t0.x;
        accB0.y += aB * w0.y + xB * t0.y;
        accB0.z += aB * w0.z + xB * t0.z;
        accB0.w += aB * w0.w + xB * t0.w;
        accB1.x += aB * w1.x + xB * t1.x;
        accB1.y += aB * w1.y + xB * t1.y;
        accB1.z += aB * w1.z + xB * t1.z;
        accB1.w += aB * w1.w + xB * t1.w;
    }

    int nA = n0 + slot;
    int nB = nA + SLOTS;
    if (nA < nNodes) {
        float4 o0, o1;
        o0.x = elu_f(accA0.x); o0.y = elu_f(accA0.y); o0.z = elu_f(accA0.z); o0.w = elu_f(accA0.w);
        o1.x = elu_f(accA1.x); o1.y = elu_f(accA1.y); o1.z = elu_f(accA1.z); o1.w = elu_f(accA1.w);
        *reinterpret_cast<float4*>(out + (size_t)nA * DOUT + j0)     = o0;
        *reinterpret_cast<float4*>(out + (size_t)nA * DOUT + j0 + 4) = o1;
    }
    if (nB < nNodes) {
        float4 o0, o1;
        o0.x = elu_f(accB0.x); o0.y = elu_f(accB0.y); o0.z = elu_f(accB0.z); o0.w = elu_f(accB0.w);
        o1.x = elu_f(accB1.x); o1.y = elu_f(accB1.y); o1.z = elu_f(accB1.z); o1.w = elu_f(accB1.w);
        *reinterpret_cast<float4*>(out + (size_t)nB * DOUT + j0)     = o0;
        *reinterpret_cast<float4*>(out + (size_t)nB * DOUT + j0 + 4) = o1;
    }
}

// ---------------------------------------------------------------------------
// Mean-pool over sorted `batch`.
// ---------------------------------------------------------------------------
#define POOL_CHUNK 256
__global__ __launch_bounds__(64) void pool_kernel(
    const float* __restrict__ h, const int* __restrict__ batch,
    float* __restrict__ sums, float* __restrict__ cnts, int nNodes)
{
    int j = threadIdx.x;
    int start = blockIdx.x * POOL_CHUNK;
    int end = start + POOL_CHUNK;
    if (end > nNodes) end = nNodes;
    if (start >= end) return;

    int g = batch[start];
    float acc = 0.f;
    float c = 0.f;
    for (int n = start; n < end; ++n) {
        int gn = batch[n];
        if (gn != g) {
            unsafeAtomicAdd(&sums[(size_t)g * 64 + j], acc);
            if (j == 0) unsafeAtomicAdd(&cnts[g], c);
            acc = 0.f; c = 0.f; g = gn;
        }
        acc += h[(size_t)n * 64 + j];
        c += 1.f;
    }
    unsafeAtomicAdd(&sums[(size_t)g * 64 + j], acc);
    if (j == 0) unsafeAtomicAdd(&cnts[g], c);
}

// ---------------------------------------------------------------------------
// MLP head + log_softmax: one 64-thread block per graph.
// ---------------------------------------------------------------------------
__global__ __launch_bounds__(64) void mlp_kernel(
    const float* __restrict__ sums, const float* __restrict__ cnts,
    const float* __restrict__ fw1, const float* __restrict__ fb1,
    const float* __restrict__ fw2, const float* __restrict__ fb2,
    const float* __restrict__ fw3, const float* __restrict__ fb3,
    float* __restrict__ out)
{
    int g = blockIdx.x;
    int j = threadIdx.x;
    __shared__ float p[64];
    __shared__ float z1[64];
    __shared__ float z2[32];
    __shared__ float z3[10];
    __shared__ float lse;

    float c = fmaxf(cnts[g], 1.f);
    p[j] = sums[(size_t)g * 64 + j] / c;
    __syncthreads();

    float a = fb1[j];
#pragma unroll
    for (int k = 0; k < 64; ++k) a += p[k] * fw1[k * 64 + j];
    z1[j] = elu_f(a);
    __syncthreads();

    if (j < 32) {
        float a2 = fb2[j];
#pragma unroll
        for (int k = 0; k < 64; ++k) a2 += z1[k] * fw2[k * 32 + j];
        z2[j] = elu_f(a2);
    }
    __syncthreads();

    if (j < 10) {
        float a3 = fb3[j];
#pragma unroll
        for (int k = 0; k < 32; ++k) a3 += z2[k] * fw3[k * 10 + j];
        z3[j] = a3;
    }
    __syncthreads();

    if (j == 0) {
        float m = -1e30f;
        for (int i = 0; i < 10; ++i) m = fmaxf(m, z3[i]);
        float s = 0.f;
        for (int i = 0; i < 10; ++i) s += expf(z3[i] - m);
        lse = logf(s) + m;
    }
    __syncthreads();

    if (j < 10) out[(size_t)g * 10 + j] = z3[j] - lse;
}

// ---------------------------------------------------------------------------
extern "C" void kernel_launch(void* const* d_in, const int* in_sizes, int n_in,
                              void* d_out, int out_size, void* d_ws, size_t ws_size,
                              hipStream_t stream)
{
    const float* x       = (const float*)d_in[0];
    const int*   ei      = (const int*)  d_in[1];
    const int*   batch   = (const int*)  d_in[2];
    const float* w1_rel  = (const float*)d_in[3];
    const float* b1      = (const float*)d_in[4];
    const float* w1_root = (const float*)d_in[5];
    const float* w2_rel  = (const float*)d_in[6];
    const float* b2      = (const float*)d_in[7];
    const float* w2_root = (const float*)d_in[8];
    const float* w3_rel  = (const float*)d_in[9];
    const float* b3      = (const float*)d_in[10];
    const float* w3_root = (const float*)d_in[11];
    const float* fw1     = (const float*)d_in[12];
    const float* fb1     = (const float*)d_in[13];
    const float* fw2     = (const float*)d_in[14];
    const float* fb2     = (const float*)d_in[15];
    const float* fw3     = (const float*)d_in[16];
    const float* fb3     = (const float*)d_in[17];
    float* out = (float*)d_out;

    const int* src = ei;
    const int* dst = ei + N_EDGES_C;

    // workspace layout
    float* agg  = (float*)d_ws;                          // N*64 f
    float* hB   = agg  + (size_t)N_NODES_C * 64;         // N*64 f
    float* hC   = hB   + (size_t)N_NODES_C * 64;         // N*64 f
    float* sums = hC   + (size_t)N_NODES_C * 64;         // 512*64 f
    float* cnts = sums + (size_t)N_GRAPHS_C * 64;        // 512 f
    int*   deg  = (int*)(cnts + N_GRAPHS_C);             // N int
    int*   row_start = deg + N_NODES_C;                  // N+1 int
    int*   bsum = row_start + N_NODES_C + 1;             // SCAN_NB int
    int*   cursor = bsum + SCAN_NB;                      // NBUCK int
    int*   ssrc = cursor + NBUCK;                        // nE int
    // ebuf (nE int2 = 12.8MB) aliased over hC (25.6MB): CSR build finishes
    // before layer 2 writes hC.
    int2*  ebuf = (int2*)hC;

    const int nb = (N_NODES_C + SCAN_CHUNK - 1) / SCAN_CHUNK;  // 98

    // ---- CSR build ----
    hipMemsetAsync(deg, 0, (size_t)N_NODES_C * sizeof(int), stream);
    hist_kernel<<<(N_EDGES_C + 255) / 256, 256, 0, stream>>>(dst, deg, N_EDGES_C);
    scan_pass1<<<nb, 256, 0, stream>>>(deg, bsum, N_NODES_C);
    scan_pass2<<<1, 128, 0, stream>>>(bsum, nb);
    scan_pass3<<<nb, 256, 0, stream>>>(deg, bsum, row_start, N_NODES_C);
    cursor_init<<<(NBUCK + 63) / 64, 64, 0, stream>>>(row_start, cursor);
    bucket_pass<<<(N_EDGES_C + CHUNK_A - 1) / CHUNK_A, 256, 0, stream>>>(
        src, dst, cursor, ebuf, N_EDGES_C);
    bucket_fill<<<NBUCK, 256, 0, stream>>>(row_start, ebuf, ssrc);

    // ---- layer 1: 32 -> 32, x -> hB ----
    gather_agg<32><<<(N_NODES_C + 31) / 32, 256, 0, stream>>>(x, row_start, ssrc, agg, N_NODES_C);
    transform_v4<32, 32><<<(N_NODES_C + 127) / 128, 256, 0, stream>>>(
        agg, x, w1_rel, b1, w1_root, hB, N_NODES_C);

    // ---- layer 2: 32 -> 64, hB -> hC ----
    gather_agg<32><<<(N_NODES_C + 31) / 32, 256, 0, stream>>>(hB, row_start, ssrc, agg, N_NODES_C);
    transform_v4<32, 64><<<(N_NODES_C + 63) / 64, 256, 0, stream>>>(
        agg, hB, w2_rel, b2, w2_root, hC, N_NODES_C);

    // ---- layer 3: 64 -> 64, hC -> hB ----
    gather_agg<64><<<(N_NODES_C + 15) / 16, 256, 0, stream>>>(hC, row_start, ssrc, agg, N_NODES_C);
    transform_v4<64, 64><<<(N_NODES_C + 63) / 64, 256, 0, stream>>>(
        agg, hC, w3_rel, b3, w3_root, hB, N_NODES_C);

    // ---- mean pool ----
    hipMemsetAsync(sums, 0, ((size_t)N_GRAPHS_C * 64 + N_GRAPHS_C) * sizeof(float), stream);
    pool_kernel<<<(N_NODES_C + POOL_CHUNK - 1) / POOL_CHUNK, 64, 0, stream>>>(
        hB, batch, sums, cnts, N_NODES_C);

    // ---- MLP head + log_softmax ----
    mlp_kernel<<<N_GRAPHS_C, 64, 0, stream>>>(
        sums, cnts, fw1, fb1, fw2, fb2, fw3, fb3, out);
}

// Round 8
// 374.448 us; speedup vs baseline: 1.3712x; 1.1238x over previous
//
#include <hip/hip_runtime.h>
#include <hip/hip_bf16.h>
#include <math.h>

#define N_NODES_C 100000
#define N_EDGES_C 1600000
#define N_GRAPHS_C 512
#define SCAN_CHUNK 1024
#define SCAN_NB ((N_NODES_C + SCAN_CHUNK) / SCAN_CHUNK + 1)
#define BSHIFT 10
#define NBUCK ((N_NODES_C + (1 << BSHIFT) - 1) >> BSHIFT)   // 98
#define CHUNK_A 8192

__device__ __forceinline__ float elu_f(float x) { return x > 0.f ? x : expm1f(x); }

__device__ __forceinline__ int wave_incl_scan(int v) {
    int lane = threadIdx.x & 63;
#pragma unroll
    for (int o = 1; o < 64; o <<= 1) {
        int t = __shfl_up(v, o);
        if (lane >= o) v += t;
    }
    return v;
}

__device__ __forceinline__ int wave_sum_i(int v) {
#pragma unroll
    for (int o = 32; o > 0; o >>= 1) v += __shfl_xor(v, o);
    return v;
}

// ---------------------------------------------------------------------------
// CSR build: histogram of in-degrees + exclusive scan -> row_start.
// ---------------------------------------------------------------------------
__global__ __launch_bounds__(256) void hist_kernel(
    const int* __restrict__ dst, int* __restrict__ deg, int nE)
{
    int e = blockIdx.x * 256 + threadIdx.x;
    if (e < nE) atomicAdd(&deg[dst[e]], 1);
}

__global__ __launch_bounds__(256) void scan_pass1(
    const int* __restrict__ deg, int* __restrict__ bsum, int n)
{
    int base = blockIdx.x * SCAN_CHUNK;
    int s = 0;
    for (int i = threadIdx.x; i < SCAN_CHUNK; i += 256) {
        int idx = base + i;
        if (idx < n) s += deg[idx];
    }
    s = wave_sum_i(s);
    __shared__ int ws[4];
    int lane = threadIdx.x & 63, w = threadIdx.x >> 6;
    if (lane == 0) ws[w] = s;
    __syncthreads();
    if (threadIdx.x == 0) bsum[blockIdx.x] = ws[0] + ws[1] + ws[2] + ws[3];
}

__global__ __launch_bounds__(128) void scan_pass2(int* __restrict__ bsum, int nb)
{
    int tid = threadIdx.x;
    int v = tid < nb ? bsum[tid] : 0;
    int lane = tid & 63, w = tid >> 6;
    int incl = wave_incl_scan(v);
    __shared__ int ws[2];
    if (lane == 63) ws[w] = incl;
    __syncthreads();
    int off = (w == 1) ? ws[0] : 0;
    if (tid < nb) bsum[tid] = off + incl - v;  // exclusive
}

__global__ __launch_bounds__(256) void scan_pass3(
    const int* __restrict__ deg, const int* __restrict__ bsum,
    int* __restrict__ row_start, int n)
{
    int base = blockIdx.x * SCAN_CHUNK + threadIdx.x * 4;
    int v[4];
#pragma unroll
    for (int k = 0; k < 4; ++k) {
        int idx = base + k;
        v[k] = (idx < n) ? deg[idx] : 0;
    }
    int lsum = v[0] + v[1] + v[2] + v[3];
    int incl = wave_incl_scan(lsum);
    __shared__ int ws[4];
    int lane = threadIdx.x & 63, w = threadIdx.x >> 6;
    if (lane == 63) ws[w] = incl;
    __syncthreads();
    int woff = 0;
    for (int i = 0; i < w; ++i) woff += ws[i];
    int p = bsum[blockIdx.x] + woff + incl - lsum;
#pragma unroll
    for (int k = 0; k < 4; ++k) {
        int idx = base + k;
        if (idx <= n) row_start[idx] = p;
        p += v[k];
    }
}

// ---------------------------------------------------------------------------
// Bucketed edge sort (contiguous writes; replaces random-write fill).
// ---------------------------------------------------------------------------
__global__ __launch_bounds__(64) void cursor_init(
    const int* __restrict__ row_start, int* __restrict__ cursor)
{
    int b = blockIdx.x * 64 + threadIdx.x;
    if (b < NBUCK) {
        int n = b << BSHIFT;
        if (n > N_NODES_C) n = N_NODES_C;
        cursor[b] = row_start[n];
    }
}

__global__ __launch_bounds__(256) void bucket_pass(
    const int* __restrict__ src, const int* __restrict__ dst,
    int* __restrict__ cursor, int2* __restrict__ ebuf, int nE)
{
    __shared__ int cnt[NBUCK];
    __shared__ int base[NBUCK];
    int t = threadIdx.x;
    for (int i = t; i < NBUCK; i += 256) cnt[i] = 0;
    __syncthreads();

    int lo = blockIdx.x * CHUNK_A;
    int hi = lo + CHUNK_A;
    if (hi > nE) hi = nE;

    for (int e = lo + t; e < hi; e += 256)
        atomicAdd(&cnt[dst[e] >> BSHIFT], 1);
    __syncthreads();

    for (int i = t; i < NBUCK; i += 256)
        base[i] = cnt[i] ? atomicAdd(&cursor[i], cnt[i]) : 0;
    __syncthreads();
    for (int i = t; i < NBUCK; i += 256) cnt[i] = 0;
    __syncthreads();

    for (int e = lo + t; e < hi; e += 256) {
        int d = dst[e];
        int b = d >> BSHIFT;
        int p = base[b] + atomicAdd(&cnt[b], 1);
        ebuf[p] = make_int2(src[e], d);
    }
}

__global__ __launch_bounds__(256) void bucket_fill(
    const int* __restrict__ row_start, const int2* __restrict__ ebuf,
    int* __restrict__ ssrc)
{
    int b = blockIdx.x;
    int nlo = b << BSHIFT;
    int nhi = nlo + (1 << BSHIFT);
    if (nhi > N_NODES_C) nhi = N_NODES_C;

    __shared__ int pos_l[1 << BSHIFT];
    int t = threadIdx.x;
    for (int i = t; i < nhi - nlo; i += 256) pos_l[i] = row_start[nlo + i];
    __syncthreads();

    int lo = row_start[nlo];
    int hi = row_start[nhi];
    for (int e = lo + t; e < hi; e += 256) {
        int2 sd = ebuf[e];
        int p = atomicAdd(&pos_l[sd.y - nlo], 1);
        ssrc[p] = sd.x;
    }
}

// ---------------------------------------------------------------------------
// Gather-sum aggregation (measured-good).
// ---------------------------------------------------------------------------
template<int D>
__global__ __launch_bounds__(256) void gather_agg(
    const float* __restrict__ x, const int* __restrict__ row_start,
    const int* __restrict__ ssrc, float* __restrict__ agg, int nNodes)
{
    const int L = D / 4;
    const int NPB = 256 / L;
    int local = threadIdx.x / L;
    int lane  = threadIdx.x % L;
    int n = blockIdx.x * NPB + local;
    if (n >= nNodes) return;
    int beg = row_start[n], end = row_start[n + 1];
    float4 acc = make_float4(0.f, 0.f, 0.f, 0.f);
    int e = beg;
    for (; e + 1 < end; e += 2) {
        int s0 = ssrc[e], s1 = ssrc[e + 1];
        float4 v0 = *reinterpret_cast<const float4*>(x + (size_t)s0 * D + lane * 4);
        float4 v1 = *reinterpret_cast<const float4*>(x + (size_t)s1 * D + lane * 4);
        acc.x += v0.x + v1.x; acc.y += v0.y + v1.y;
        acc.z += v0.z + v1.z; acc.w += v0.w + v1.w;
    }
    if (e < end) {
        int s0 = ssrc[e];
        float4 v0 = *reinterpret_cast<const float4*>(x + (size_t)s0 * D + lane * 4);
        acc.x += v0.x; acc.y += v0.y; acc.z += v0.z; acc.w += v0.w;
    }
    *reinterpret_cast<float4*>(agg + (size_t)n * D + lane * 4) = acc;
}

// ---------------------------------------------------------------------------
// Node transform v4 (measured-good): LDS-staged inputs, 2 nodes x 8 outputs
// per thread, rolled k-loop (full unroll spilled at 256 VGPRs).
// ---------------------------------------------------------------------------
template<int DIN, int DOUT>
__global__ __launch_bounds__(256) void transform_v4(
    const float* __restrict__ agg, const float* __restrict__ xin,
    const float* __restrict__ w_rel, const float* __restrict__ bias,
    const float* __restrict__ w_root, float* __restrict__ out, int nNodes)
{
    constexpr int JB = 8;
    constexpr int TPN = DOUT / JB;
    constexpr int SLOTS = 256 / TPN;
    constexpr int NT = 2;
    constexpr int NPB = SLOTS * NT;
    constexpr int PITCH = DIN + 4;

    __shared__ float wr[DIN * DOUT];
    __shared__ float wt[DIN * DOUT];
    __shared__ float a_s[NPB * PITCH];
    __shared__ float x_s[NPB * PITCH];

    {
        const float4* wr4 = reinterpret_cast<const float4*>(w_rel);
        const float4* wt4 = reinterpret_cast<const float4*>(w_root);
        float4* wrd = reinterpret_cast<float4*>(wr);
        float4* wtd = reinterpret_cast<float4*>(wt);
        for (int i = threadIdx.x; i < DIN * DOUT / 4; i += 256) {
            wrd[i] = wr4[i];
            wtd[i] = wt4[i];
        }
    }

    int n0 = blockIdx.x * NPB;
    constexpr int NV = NPB * DIN / 4;
    for (int v = threadIdx.x; v < NV; v += 256) {
        int row  = v / (DIN / 4);
        int col4 = v % (DIN / 4);
        int n = n0 + row;
        float4 a = make_float4(0.f, 0.f, 0.f, 0.f);
        float4 xx = a;
        if (n < nNodes) {
            a  = *reinterpret_cast<const float4*>(agg + (size_t)n * DIN + col4 * 4);
            xx = *reinterpret_cast<const float4*>(xin + (size_t)n * DIN + col4 * 4);
        }
        *reinterpret_cast<float4*>(&a_s[row * PITCH + col4 * 4]) = a;
        *reinterpret_cast<float4*>(&x_s[row * PITCH + col4 * 4]) = xx;
    }
    __syncthreads();

    int slot = threadIdx.x / TPN;
    int j0 = (threadIdx.x % TPN) * JB;

    float4 biasLo = *reinterpret_cast<const float4*>(bias + j0);
    float4 biasHi = *reinterpret_cast<const float4*>(bias + j0 + 4);
    float4 accA0 = biasLo, accA1 = biasHi;
    float4 accB0 = biasLo, accB1 = biasHi;

    const float* arA = &a_s[slot * PITCH];
    const float* xrA = &x_s[slot * PITCH];
    const float* arB = arA + SLOTS * PITCH;
    const float* xrB = xrA + SLOTS * PITCH;

#pragma unroll 2
    for (int k = 0; k < DIN; ++k) {
        float aA = arA[k], xA = xrA[k];
        float aB = arB[k], xB = xrB[k];
        float4 w0 = *reinterpret_cast<const float4*>(&wr[k * DOUT + j0]);
        float4 w1 = *reinterpret_cast<const float4*>(&wr[k * DOUT + j0 + 4]);
        float4 t0 = *reinterpret_cast<const float4*>(&wt[k * DOUT + j0]);
        float4 t1 = *reinterpret_cast<const float4*>(&wt[k * DOUT + j0 + 4]);
        accA0.x += aA * w0.x + xA * t0.x;
        accA0.y += aA * w0.y + xA * t0.y;
        accA0.z += aA * w0.z + xA * t0.z;
        accA0.w += aA * w0.w + xA * t0.w;
        accA1.x += aA * w1.x + xA * t1.x;
        accA1.y += aA * w1.y + xA * t1.y;
        accA1.z += aA * w1.z + xA * t1.z;
        accA1.w += aA * w1.w + xA * t1.w;
        accB0.x += aB * w0.x + xB * t0.x;
        accB0.y += aB * w0.y + xB * t0.y;
        accB0.z += aB * w0.z + xB * t0.z;
        accB0.w += aB * w0.w + xB * t0.w;
        accB1.x += aB * w1.x + xB * t1.x;
        accB1.y += aB * w1.y + xB * t1.y;
        accB1.z += aB * w1.z + xB * t1.z;
        accB1.w += aB * w1.w + xB * t1.w;
    }

    int nA = n0 + slot;
    int nB = nA + SLOTS;
    if (nA < nNodes) {
        float4 o0, o1;
        o0.x = elu_f(accA0.x); o0.y = elu_f(accA0.y); o0.z = elu_f(accA0.z); o0.w = elu_f(accA0.w);
        o1.x = elu_f(accA1.x); o1.y = elu_f(accA1.y); o1.z = elu_f(accA1.z); o1.w = elu_f(accA1.w);
        *reinterpret_cast<float4*>(out + (size_t)nA * DOUT + j0)     = o0;
        *reinterpret_cast<float4*>(out + (size_t)nA * DOUT + j0 + 4) = o1;
    }
    if (nB < nNodes) {
        float4 o0, o1;
        o0.x = elu_f(accB0.x); o0.y = elu_f(accB0.y); o0.z = elu_f(accB0.z); o0.w = elu_f(accB0.w);
        o1.x = elu_f(accB1.x); o1.y = elu_f(accB1.y); o1.z = elu_f(accB1.z); o1.w = elu_f(accB1.w);
        *reinterpret_cast<float4*>(out + (size_t)nB * DOUT + j0)     = o0;
        *reinterpret_cast<float4*>(out + (size_t)nB * DOUT + j0 + 4) = o1;
    }
}

// ---------------------------------------------------------------------------
// Mean-pool v2: 256 threads/block = (sub 0..3, feat 0..63); each sub-lane
// strides 4 nodes through the block's 256-node chunk. batch sorted ->
// per-thread graph IDs non-decreasing -> running accumulate + atomic flush
// on boundary. 4x the waves of v1; 4 independent load streams per block.
// ---------------------------------------------------------------------------
#define POOL_CHUNK 256
__global__ __launch_bounds__(256) void pool_kernel2(
    const float* __restrict__ h, const int* __restrict__ batch,
    float* __restrict__ sums, float* __restrict__ cnts, int nNodes)
{
    int t = threadIdx.x;
    int j = t & 63;        // feature
    int sub = t >> 6;      // 0..3
    int start = blockIdx.x * POOL_CHUNK + sub;
    int end = blockIdx.x * POOL_CHUNK + POOL_CHUNK;
    if (end > nNodes) end = nNodes;
    if (start >= end) return;

    int g = batch[start];
    float acc = 0.f;
    float c = 0.f;
    for (int n = start; n < end; n += 4) {
        int gn = batch[n];
        if (gn != g) {
            unsafeAtomicAdd(&sums[(size_t)g * 64 + j], acc);
            if (j == 0) unsafeAtomicAdd(&cnts[g], c);
            acc = 0.f; c = 0.f; g = gn;
        }
        acc += h[(size_t)n * 64 + j];
        c += 1.f;
    }
    unsafeAtomicAdd(&sums[(size_t)g * 64 + j], acc);
    if (j == 0) unsafeAtomicAdd(&cnts[g], c);
}

// ---------------------------------------------------------------------------
// MLP head + log_softmax: one 64-thread block per graph.
// ---------------------------------------------------------------------------
__global__ __launch_bounds__(64) void mlp_kernel(
    const float* __restrict__ sums, const float* __restrict__ cnts,
    const float* __restrict__ fw1, const float* __restrict__ fb1,
    const float* __restrict__ fw2, const float* __restrict__ fb2,
    const float* __restrict__ fw3, const float* __restrict__ fb3,
    float* __restrict__ out)
{
    int g = blockIdx.x;
    int j = threadIdx.x;
    __shared__ float p[64];
    __shared__ float z1[64];
    __shared__ float z2[32];
    __shared__ float z3[10];
    __shared__ float lse;

    float c = fmaxf(cnts[g], 1.f);
    p[j] = sums[(size_t)g * 64 + j] / c;
    __syncthreads();

    float a = fb1[j];
#pragma unroll
    for (int k = 0; k < 64; ++k) a += p[k] * fw1[k * 64 + j];
    z1[j] = elu_f(a);
    __syncthreads();

    if (j < 32) {
        float a2 = fb2[j];
#pragma unroll
        for (int k = 0; k < 64; ++k) a2 += z1[k] * fw2[k * 32 + j];
        z2[j] = elu_f(a2);
    }
    __syncthreads();

    if (j < 10) {
        float a3 = fb3[j];
#pragma unroll
        for (int k = 0; k < 32; ++k) a3 += z2[k] * fw3[k * 10 + j];
        z3[j] = a3;
    }
    __syncthreads();

    if (j == 0) {
        float m = -1e30f;
        for (int i = 0; i < 10; ++i) m = fmaxf(m, z3[i]);
        float s = 0.f;
        for (int i = 0; i < 10; ++i) s += expf(z3[i] - m);
        lse = logf(s) + m;
    }
    __syncthreads();

    if (j < 10) out[(size_t)g * 10 + j] = z3[j] - lse;
}

// ---------------------------------------------------------------------------
extern "C" void kernel_launch(void* const* d_in, const int* in_sizes, int n_in,
                              void* d_out, int out_size, void* d_ws, size_t ws_size,
                              hipStream_t stream)
{
    const float* x       = (const float*)d_in[0];
    const int*   ei      = (const int*)  d_in[1];
    const int*   batch   = (const int*)  d_in[2];
    const float* w1_rel  = (const float*)d_in[3];
    const float* b1      = (const float*)d_in[4];
    const float* w1_root = (const float*)d_in[5];
    const float* w2_rel  = (const float*)d_in[6];
    const float* b2      = (const float*)d_in[7];
    const float* w2_root = (const float*)d_in[8];
    const float* w3_rel  = (const float*)d_in[9];
    const float* b3      = (const float*)d_in[10];
    const float* w3_root = (const float*)d_in[11];
    const float* fw1     = (const float*)d_in[12];
    const float* fb1     = (const float*)d_in[13];
    const float* fw2     = (const float*)d_in[14];
    const float* fb2     = (const float*)d_in[15];
    const float* fw3     = (const float*)d_in[16];
    const float* fb3     = (const float*)d_in[17];
    float* out = (float*)d_out;

    const int* src = ei;
    const int* dst = ei + N_EDGES_C;

    // workspace layout
    float* agg  = (float*)d_ws;                          // N*64 f
    float* hB   = agg  + (size_t)N_NODES_C * 64;         // N*64 f
    float* hC   = hB   + (size_t)N_NODES_C * 64;         // N*64 f
    float* sums = hC   + (size_t)N_NODES_C * 64;         // 512*64 f
    float* cnts = sums + (size_t)N_GRAPHS_C * 64;        // 512 f
    int*   deg  = (int*)(cnts + N_GRAPHS_C);             // N int
    int*   row_start = deg + N_NODES_C;                  // N+1 int
    int*   bsum = row_start + N_NODES_C + 1;             // SCAN_NB int
    int*   cursor = bsum + SCAN_NB;                      // NBUCK int
    int*   ssrc = cursor + NBUCK;                        // nE int
    int2*  ebuf = (int2*)hC;  // aliased: CSR build done before hC written

    const int nb = (N_NODES_C + SCAN_CHUNK - 1) / SCAN_CHUNK;  // 98

    // ---- CSR build ----
    hipMemsetAsync(deg, 0, (size_t)N_NODES_C * sizeof(int), stream);
    hist_kernel<<<(N_EDGES_C + 255) / 256, 256, 0, stream>>>(dst, deg, N_EDGES_C);
    scan_pass1<<<nb, 256, 0, stream>>>(deg, bsum, N_NODES_C);
    scan_pass2<<<1, 128, 0, stream>>>(bsum, nb);
    scan_pass3<<<nb, 256, 0, stream>>>(deg, bsum, row_start, N_NODES_C);
    cursor_init<<<(NBUCK + 63) / 64, 64, 0, stream>>>(row_start, cursor);
    bucket_pass<<<(N_EDGES_C + CHUNK_A - 1) / CHUNK_A, 256, 0, stream>>>(
        src, dst, cursor, ebuf, N_EDGES_C);
    bucket_fill<<<NBUCK, 256, 0, stream>>>(row_start, ebuf, ssrc);

    // ---- layer 1: 32 -> 32, x -> hB ----
    gather_agg<32><<<(N_NODES_C + 31) / 32, 256, 0, stream>>>(x, row_start, ssrc, agg, N_NODES_C);
    transform_v4<32, 32><<<(N_NODES_C + 127) / 128, 256, 0, stream>>>(
        agg, x, w1_rel, b1, w1_root, hB, N_NODES_C);

    // ---- layer 2: 32 -> 64, hB -> hC ----
    gather_agg<32><<<(N_NODES_C + 31) / 32, 256, 0, stream>>>(hB, row_start, ssrc, agg, N_NODES_C);
    transform_v4<32, 64><<<(N_NODES_C + 63) / 64, 256, 0, stream>>>(
        agg, hB, w2_rel, b2, w2_root, hC, N_NODES_C);

    // ---- layer 3: 64 -> 64, hC -> hB ----
    gather_agg<64><<<(N_NODES_C + 15) / 16, 256, 0, stream>>>(hC, row_start, ssrc, agg, N_NODES_C);
    transform_v4<64, 64><<<(N_NODES_C + 63) / 64, 256, 0, stream>>>(
        agg, hC, w3_rel, b3, w3_root, hB, N_NODES_C);

    // ---- mean pool ----
    hipMemsetAsync(sums, 0, ((size_t)N_GRAPHS_C * 64 + N_GRAPHS_C) * sizeof(float), stream);
    pool_kernel2<<<(N_NODES_C + POOL_CHUNK - 1) / POOL_CHUNK, 256, 0, stream>>>(
        hB, batch, sums, cnts, N_NODES_C);

    // ---- MLP head + log_softmax ----
    mlp_kernel<<<N_GRAPHS_C, 64, 0, stream>>>(
        sums, cnts, fw1, fb1, fw2, fb2, fw3, fb3, out);
}

// Round 9
// 332.787 us; speedup vs baseline: 1.5428x; 1.1252x over previous
//
#include <hip/hip_runtime.h>
#include <hip/hip_bf16.h>
#include <math.h>

#define N_NODES_C 100000
#define N_EDGES_C 1600000
#define N_GRAPHS_C 512
#define BSHIFT 10
#define BSIZE (1 << BSHIFT)
#define NBUCK ((N_NODES_C + BSIZE - 1) >> BSHIFT)   // 98
#define CHUNK_A 8192

__device__ __forceinline__ float elu_f(float x) { return x > 0.f ? x : expm1f(x); }

__device__ __forceinline__ int wave_incl_scan(int v) {
    int lane = threadIdx.x & 63;
#pragma unroll
    for (int o = 1; o < 64; o <<= 1) {
        int t = __shfl_up(v, o);
        if (lane >= o) v += t;
    }
    return v;
}

// ---------------------------------------------------------------------------
// Bucketed CSR build. No global histogram, no global scan over nodes:
//   1) bucket_count: per-chunk LDS histogram of dst>>BSHIFT -> global bcnt
//   2) bucket_scan (1 block): exclusive scan of 98 bucket counts
//   3) bucket_pass: partition (src,dst) pairs into per-bucket ebuf regions
//   4) bucket_build: per bucket, LDS deg-histogram + LDS scan -> row_start
//      (coalesced) + positioned ssrc fill confined to the bucket's window
// ---------------------------------------------------------------------------
__global__ __launch_bounds__(256) void bucket_count(
    const int* __restrict__ dst, int* __restrict__ bcnt, int nE)
{
    __shared__ int cnt[NBUCK];
    int t = threadIdx.x;
    for (int i = t; i < NBUCK; i += 256) cnt[i] = 0;
    __syncthreads();
    int lo = blockIdx.x * CHUNK_A;
    int hi = lo + CHUNK_A;
    if (hi > nE) hi = nE;
    for (int e = lo + t; e < hi; e += 256)
        atomicAdd(&cnt[dst[e] >> BSHIFT], 1);
    __syncthreads();
    for (int i = t; i < NBUCK; i += 256)
        if (cnt[i]) atomicAdd(&bcnt[i], cnt[i]);
}

__global__ __launch_bounds__(128) void bucket_scan(
    const int* __restrict__ bcnt, int* __restrict__ bucket_base,
    int* __restrict__ cursor, int nE)
{
    int tid = threadIdx.x;  // NBUCK <= 128
    int v = tid < NBUCK ? bcnt[tid] : 0;
    int lane = tid & 63, w = tid >> 6;
    int incl = wave_incl_scan(v);
    __shared__ int ws[2];
    if (lane == 63) ws[w] = incl;
    __syncthreads();
    int off = (w == 1) ? ws[0] : 0;
    int excl = off + incl - v;
    if (tid < NBUCK) {
        bucket_base[tid] = excl;
        cursor[tid] = excl;
    }
    if (tid == 0) bucket_base[NBUCK] = nE;
}

__global__ __launch_bounds__(256) void bucket_pass(
    const int* __restrict__ src, const int* __restrict__ dst,
    int* __restrict__ cursor, int2* __restrict__ ebuf, int nE)
{
    __shared__ int cnt[NBUCK];
    __shared__ int base[NBUCK];
    int t = threadIdx.x;
    for (int i = t; i < NBUCK; i += 256) cnt[i] = 0;
    __syncthreads();

    int lo = blockIdx.x * CHUNK_A;
    int hi = lo + CHUNK_A;
    if (hi > nE) hi = nE;

    for (int e = lo + t; e < hi; e += 256)
        atomicAdd(&cnt[dst[e] >> BSHIFT], 1);
    __syncthreads();

    for (int i = t; i < NBUCK; i += 256)
        base[i] = cnt[i] ? atomicAdd(&cursor[i], cnt[i]) : 0;
    __syncthreads();
    for (int i = t; i < NBUCK; i += 256) cnt[i] = 0;
    __syncthreads();

    for (int e = lo + t; e < hi; e += 256) {
        int d = dst[e];
        int b = d >> BSHIFT;
        int p = base[b] + atomicAdd(&cnt[b], 1);
        ebuf[p] = make_int2(src[e], d);
    }
}

__global__ __launch_bounds__(256) void bucket_build(
    const int* __restrict__ bucket_base, const int2* __restrict__ ebuf,
    int* __restrict__ row_start, int* __restrict__ ssrc)
{
    int b = blockIdx.x;
    int nlo = b << BSHIFT;
    int nhi = nlo + BSIZE;
    if (nhi > N_NODES_C) nhi = N_NODES_C;
    int nloc = nhi - nlo;

    __shared__ int degl[BSIZE];
    __shared__ int posl[BSIZE];
    __shared__ int ws[4];
    int t = threadIdx.x;

    for (int i = t; i < BSIZE; i += 256) degl[i] = 0;
    __syncthreads();

    int lo = bucket_base[b];
    int hi = bucket_base[b + 1];
    for (int e = lo + t; e < hi; e += 256)
        atomicAdd(&degl[ebuf[e].y - nlo], 1);
    __syncthreads();

    // block exclusive scan over BSIZE elements (4 per thread)
    int base4 = t * 4;
    int v0 = degl[base4 + 0], v1 = degl[base4 + 1];
    int v2 = degl[base4 + 2], v3 = degl[base4 + 3];
    int lsum = v0 + v1 + v2 + v3;
    int incl = wave_incl_scan(lsum);
    int lane = t & 63, w = t >> 6;
    if (lane == 63) ws[w] = incl;
    __syncthreads();
    int woff = 0;
    for (int i = 0; i < w; ++i) woff += ws[i];
    int p = lo + woff + incl - lsum;
    // write row_start (coalesced-ish) + posl cursors
    int pp = p;
    if (base4 + 0 < nloc) { row_start[nlo + base4 + 0] = pp; posl[base4 + 0] = pp; } pp += v0;
    if (base4 + 1 < nloc) { row_start[nlo + base4 + 1] = pp; posl[base4 + 1] = pp; } pp += v1;
    if (base4 + 2 < nloc) { row_start[nlo + base4 + 2] = pp; posl[base4 + 2] = pp; } pp += v2;
    if (base4 + 3 < nloc) { row_start[nlo + base4 + 3] = pp; posl[base4 + 3] = pp; } pp += v3;
    if (t == 0 && nhi == N_NODES_C) row_start[N_NODES_C] = hi;
    __syncthreads();

    // positioned fill within the bucket's contiguous ssrc window
    for (int e = lo + t; e < hi; e += 256) {
        int2 sd = ebuf[e];
        int q = atomicAdd(&posl[sd.y - nlo], 1);
        ssrc[q] = sd.x;
    }
}

// ---------------------------------------------------------------------------
// Gather-sum aggregation (measured-good).
// ---------------------------------------------------------------------------
template<int D>
__global__ __launch_bounds__(256) void gather_agg(
    const float* __restrict__ x, const int* __restrict__ row_start,
    const int* __restrict__ ssrc, float* __restrict__ agg, int nNodes)
{
    const int L = D / 4;
    const int NPB = 256 / L;
    int local = threadIdx.x / L;
    int lane  = threadIdx.x % L;
    int n = blockIdx.x * NPB + local;
    if (n >= nNodes) return;
    int beg = row_start[n], end = row_start[n + 1];
    float4 acc = make_float4(0.f, 0.f, 0.f, 0.f);
    int e = beg;
    for (; e + 1 < end; e += 2) {
        int s0 = ssrc[e], s1 = ssrc[e + 1];
        float4 v0 = *reinterpret_cast<const float4*>(x + (size_t)s0 * D + lane * 4);
        float4 v1 = *reinterpret_cast<const float4*>(x + (size_t)s1 * D + lane * 4);
        acc.x += v0.x + v1.x; acc.y += v0.y + v1.y;
        acc.z += v0.z + v1.z; acc.w += v0.w + v1.w;
    }
    if (e < end) {
        int s0 = ssrc[e];
        float4 v0 = *reinterpret_cast<const float4*>(x + (size_t)s0 * D + lane * 4);
        acc.x += v0.x; acc.y += v0.y; acc.z += v0.z; acc.w += v0.w;
    }
    *reinterpret_cast<float4*>(agg + (size_t)n * D + lane * 4) = acc;
}

// ---------------------------------------------------------------------------
// Node transform v4 (measured-good): LDS-staged inputs, 2 nodes x 8 outputs
// per thread, rolled k-loop (full unroll spilled at 256 VGPRs).
// ---------------------------------------------------------------------------
template<int DIN, int DOUT>
__global__ __launch_bounds__(256) void transform_v4(
    const float* __restrict__ agg, const float* __restrict__ xin,
    const float* __restrict__ w_rel, const float* __restrict__ bias,
    const float* __restrict__ w_root, float* __restrict__ out, int nNodes)
{
    constexpr int JB = 8;
    constexpr int TPN = DOUT / JB;
    constexpr int SLOTS = 256 / TPN;
    constexpr int NT = 2;
    constexpr int NPB = SLOTS * NT;
    constexpr int PITCH = DIN + 4;

    __shared__ float wr[DIN * DOUT];
    __shared__ float wt[DIN * DOUT];
    __shared__ float a_s[NPB * PITCH];
    __shared__ float x_s[NPB * PITCH];

    {
        const float4* wr4 = reinterpret_cast<const float4*>(w_rel);
        const float4* wt4 = reinterpret_cast<const float4*>(w_root);
        float4* wrd = reinterpret_cast<float4*>(wr);
        float4* wtd = reinterpret_cast<float4*>(wt);
        for (int i = threadIdx.x; i < DIN * DOUT / 4; i += 256) {
            wrd[i] = wr4[i];
            wtd[i] = wt4[i];
        }
    }

    int n0 = blockIdx.x * NPB;
    constexpr int NV = NPB * DIN / 4;
    for (int v = threadIdx.x; v < NV; v += 256) {
        int row  = v / (DIN / 4);
        int col4 = v % (DIN / 4);
        int n = n0 + row;
        float4 a = make_float4(0.f, 0.f, 0.f, 0.f);
        float4 xx = a;
        if (n < nNodes) {
            a  = *reinterpret_cast<const float4*>(agg + (size_t)n * DIN + col4 * 4);
            xx = *reinterpret_cast<const float4*>(xin + (size_t)n * DIN + col4 * 4);
        }
        *reinterpret_cast<float4*>(&a_s[row * PITCH + col4 * 4]) = a;
        *reinterpret_cast<float4*>(&x_s[row * PITCH + col4 * 4]) = xx;
    }
    __syncthreads();

    int slot = threadIdx.x / TPN;
    int j0 = (threadIdx.x % TPN) * JB;

    float4 biasLo = *reinterpret_cast<const float4*>(bias + j0);
    float4 biasHi = *reinterpret_cast<const float4*>(bias + j0 + 4);
    float4 accA0 = biasLo, accA1 = biasHi;
    float4 accB0 = biasLo, accB1 = biasHi;

    const float* arA = &a_s[slot * PITCH];
    const float* xrA = &x_s[slot * PITCH];
    const float* arB = arA + SLOTS * PITCH;
    const float* xrB = xrA + SLOTS * PITCH;

#pragma unroll 2
    for (int k = 0; k < DIN; ++k) {
        float aA = arA[k], xA = xrA[k];
        float aB = arB[k], xB = xrB[k];
        float4 w0 = *reinterpret_cast<const float4*>(&wr[k * DOUT + j0]);
        float4 w1 = *reinterpret_cast<const float4*>(&wr[k * DOUT + j0 + 4]);
        float4 t0 = *reinterpret_cast<const float4*>(&wt[k * DOUT + j0]);
        float4 t1 = *reinterpret_cast<const float4*>(&wt[k * DOUT + j0 + 4]);
        accA0.x += aA * w0.x + xA * t0.x;
        accA0.y += aA * w0.y + xA * t0.y;
        accA0.z += aA * w0.z + xA * t0.z;
        accA0.w += aA * w0.w + xA * t0.w;
        accA1.x += aA * w1.x + xA * t1.x;
        accA1.y += aA * w1.y + xA * t1.y;
        accA1.z += aA * w1.z + xA * t1.z;
        accA1.w += aA * w1.w + xA * t1.w;
        accB0.x += aB * w0.x + xB * t0.x;
        accB0.y += aB * w0.y + xB * t0.y;
        accB0.z += aB * w0.z + xB * t0.z;
        accB0.w += aB * w0.w + xB * t0.w;
        accB1.x += aB * w1.x + xB * t1.x;
        accB1.y += aB * w1.y + xB * t1.y;
        accB1.z += aB * w1.z + xB * t1.z;
        accB1.w += aB * w1.w + xB * t1.w;
    }

    int nA = n0 + slot;
    int nB = nA + SLOTS;
    if (nA < nNodes) {
        float4 o0, o1;
        o0.x = elu_f(accA0.x); o0.y = elu_f(accA0.y); o0.z = elu_f(accA0.z); o0.w = elu_f(accA0.w);
        o1.x = elu_f(accA1.x); o1.y = elu_f(accA1.y); o1.z = elu_f(accA1.z); o1.w = elu_f(accA1.w);
        *reinterpret_cast<float4*>(out + (size_t)nA * DOUT + j0)     = o0;
        *reinterpret_cast<float4*>(out + (size_t)nA * DOUT + j0 + 4) = o1;
    }
    if (nB < nNodes) {
        float4 o0, o1;
        o0.x = elu_f(accB0.x); o0.y = elu_f(accB0.y); o0.z = elu_f(accB0.z); o0.w = elu_f(accB0.w);
        o1.x = elu_f(accB1.x); o1.y = elu_f(accB1.y); o1.z = elu_f(accB1.z); o1.w = elu_f(accB1.w);
        *reinterpret_cast<float4*>(out + (size_t)nB * DOUT + j0)     = o0;
        *reinterpret_cast<float4*>(out + (size_t)nB * DOUT + j0 + 4) = o1;
    }
}

// ---------------------------------------------------------------------------
// Mean-pool v2 (measured-good): 256 threads = (sub 0..3, feat 0..63).
// ---------------------------------------------------------------------------
#define POOL_CHUNK 256
__global__ __launch_bounds__(256) void pool_kernel2(
    const float* __restrict__ h, const int* __restrict__ batch,
    float* __restrict__ sums, float* __restrict__ cnts, int nNodes)
{
    int t = threadIdx.x;
    int j = t & 63;
    int sub = t >> 6;
    int start = blockIdx.x * POOL_CHUNK + sub;
    int end = blockIdx.x * POOL_CHUNK + POOL_CHUNK;
    if (end > nNodes) end = nNodes;
    if (start >= end) return;

    int g = batch[start];
    float acc = 0.f;
    float c = 0.f;
    for (int n = start; n < end; n += 4) {
        int gn = batch[n];
        if (gn != g) {
            unsafeAtomicAdd(&sums[(size_t)g * 64 + j], acc);
            if (j == 0) unsafeAtomicAdd(&cnts[g], c);
            acc = 0.f; c = 0.f; g = gn;
        }
        acc += h[(size_t)n * 64 + j];
        c += 1.f;
    }
    unsafeAtomicAdd(&sums[(size_t)g * 64 + j], acc);
    if (j == 0) unsafeAtomicAdd(&cnts[g], c);
}

// ---------------------------------------------------------------------------
// MLP head + log_softmax: one 64-thread block per graph.
// ---------------------------------------------------------------------------
__global__ __launch_bounds__(64) void mlp_kernel(
    const float* __restrict__ sums, const float* __restrict__ cnts,
    const float* __restrict__ fw1, const float* __restrict__ fb1,
    const float* __restrict__ fw2, const float* __restrict__ fb2,
    const float* __restrict__ fw3, const float* __restrict__ fb3,
    float* __restrict__ out)
{
    int g = blockIdx.x;
    int j = threadIdx.x;
    __shared__ float p[64];
    __shared__ float z1[64];
    __shared__ float z2[32];
    __shared__ float z3[10];
    __shared__ float lse;

    float c = fmaxf(cnts[g], 1.f);
    p[j] = sums[(size_t)g * 64 + j] / c;
    __syncthreads();

    float a = fb1[j];
#pragma unroll
    for (int k = 0; k < 64; ++k) a += p[k] * fw1[k * 64 + j];
    z1[j] = elu_f(a);
    __syncthreads();

    if (j < 32) {
        float a2 = fb2[j];
#pragma unroll
        for (int k = 0; k < 64; ++k) a2 += z1[k] * fw2[k * 32 + j];
        z2[j] = elu_f(a2);
    }
    __syncthreads();

    if (j < 10) {
        float a3 = fb3[j];
#pragma unroll
        for (int k = 0; k < 32; ++k) a3 += z2[k] * fw3[k * 10 + j];
        z3[j] = a3;
    }
    __syncthreads();

    if (j == 0) {
        float m = -1e30f;
        for (int i = 0; i < 10; ++i) m = fmaxf(m, z3[i]);
        float s = 0.f;
        for (int i = 0; i < 10; ++i) s += expf(z3[i] - m);
        lse = logf(s) + m;
    }
    __syncthreads();

    if (j < 10) out[(size_t)g * 10 + j] = z3[j] - lse;
}

// ---------------------------------------------------------------------------
extern "C" void kernel_launch(void* const* d_in, const int* in_sizes, int n_in,
                              void* d_out, int out_size, void* d_ws, size_t ws_size,
                              hipStream_t stream)
{
    const float* x       = (const float*)d_in[0];
    const int*   ei      = (const int*)  d_in[1];
    const int*   batch   = (const int*)  d_in[2];
    const float* w1_rel  = (const float*)d_in[3];
    const float* b1      = (const float*)d_in[4];
    const float* w1_root = (const float*)d_in[5];
    const float* w2_rel  = (const float*)d_in[6];
    const float* b2      = (const float*)d_in[7];
    const float* w2_root = (const float*)d_in[8];
    const float* w3_rel  = (const float*)d_in[9];
    const float* b3      = (const float*)d_in[10];
    const float* w3_root = (const float*)d_in[11];
    const float* fw1     = (const float*)d_in[12];
    const float* fb1     = (const float*)d_in[13];
    const float* fw2     = (const float*)d_in[14];
    const float* fb2     = (const float*)d_in[15];
    const float* fw3     = (const float*)d_in[16];
    const float* fb3     = (const float*)d_in[17];
    float* out = (float*)d_out;

    const int* src = ei;
    const int* dst = ei + N_EDGES_C;

    // workspace layout
    float* agg  = (float*)d_ws;                          // N*64 f
    float* hB   = agg  + (size_t)N_NODES_C * 64;         // N*64 f
    float* hC   = hB   + (size_t)N_NODES_C * 64;         // N*64 f
    float* sums = hC   + (size_t)N_NODES_C * 64;         // 512*64 f
    float* cnts = sums + (size_t)N_GRAPHS_C * 64;        // 512 f
    int*   row_start = (int*)(cnts + N_GRAPHS_C);        // N+1 int
    int*   bcnt = row_start + N_NODES_C + 1;             // NBUCK int
    int*   bucket_base = bcnt + NBUCK;                   // NBUCK+1 int
    int*   cursor = bucket_base + NBUCK + 1;             // NBUCK int
    int*   ssrc = cursor + NBUCK;                        // nE int
    int2*  ebuf = (int2*)hC;  // aliased: CSR build done before hC written

    // ---- bucketed CSR build ----
    hipMemsetAsync(bcnt, 0, NBUCK * sizeof(int), stream);
    bucket_count<<<(N_EDGES_C + CHUNK_A - 1) / CHUNK_A, 256, 0, stream>>>(
        dst, bcnt, N_EDGES_C);
    bucket_scan<<<1, 128, 0, stream>>>(bcnt, bucket_base, cursor, N_EDGES_C);
    bucket_pass<<<(N_EDGES_C + CHUNK_A - 1) / CHUNK_A, 256, 0, stream>>>(
        src, dst, cursor, ebuf, N_EDGES_C);
    bucket_build<<<NBUCK, 256, 0, stream>>>(bucket_base, ebuf, row_start, ssrc);

    // ---- layer 1: 32 -> 32, x -> hB ----
    gather_agg<32><<<(N_NODES_C + 31) / 32, 256, 0, stream>>>(x, row_start, ssrc, agg, N_NODES_C);
    transform_v4<32, 32><<<(N_NODES_C + 127) / 128, 256, 0, stream>>>(
        agg, x, w1_rel, b1, w1_root, hB, N_NODES_C);

    // ---- layer 2: 32 -> 64, hB -> hC ----
    gather_agg<32><<<(N_NODES_C + 31) / 32, 256, 0, stream>>>(hB, row_start, ssrc, agg, N_NODES_C);
    transform_v4<32, 64><<<(N_NODES_C + 63) / 64, 256, 0, stream>>>(
        agg, hB, w2_rel, b2, w2_root, hC, N_NODES_C);

    // ---- layer 3: 64 -> 64, hC -> hB ----
    gather_agg<64><<<(N_NODES_C + 15) / 16, 256, 0, stream>>>(hC, row_start, ssrc, agg, N_NODES_C);
    transform_v4<64, 64><<<(N_NODES_C + 63) / 64, 256, 0, stream>>>(
        agg, hC, w3_rel, b3, w3_root, hB, N_NODES_C);

    // ---- mean pool ----
    hipMemsetAsync(sums, 0, ((size_t)N_GRAPHS_C * 64 + N_GRAPHS_C) * sizeof(float), stream);
    pool_kernel2<<<(N_NODES_C + POOL_CHUNK - 1) / POOL_CHUNK, 256, 0, stream>>>(
        hB, batch, sums, cnts, N_NODES_C);

    // ---- MLP head + log_softmax ----
    mlp_kernel<<<N_GRAPHS_C, 64, 0, stream>>>(
        sums, cnts, fw1, fb1, fw2, fb2, fw3, fb3, out);
}

// Round 10
// 331.524 us; speedup vs baseline: 1.5487x; 1.0038x over previous
//
#include <hip/hip_runtime.h>
#include <hip/hip_bf16.h>
#include <math.h>

#define N_NODES_C 100000
#define N_EDGES_C 1600000
#define N_GRAPHS_C 512
#define BSHIFT 10
#define BSIZE (1 << BSHIFT)
#define NBUCK ((N_NODES_C + BSIZE - 1) >> BSHIFT)   // 98
#define CHUNK_A 8192

__device__ __forceinline__ float elu_f(float x) { return x > 0.f ? x : expm1f(x); }

__device__ __forceinline__ int wave_incl_scan(int v) {
    int lane = threadIdx.x & 63;
#pragma unroll
    for (int o = 1; o < 64; o <<= 1) {
        int t = __shfl_up(v, o);
        if (lane >= o) v += t;
    }
    return v;
}

// ---------------------------------------------------------------------------
// Bucketed CSR build (measured-good, round 9).
// ---------------------------------------------------------------------------
__global__ __launch_bounds__(256) void bucket_count(
    const int* __restrict__ dst, int* __restrict__ bcnt, int nE)
{
    __shared__ int cnt[NBUCK];
    int t = threadIdx.x;
    for (int i = t; i < NBUCK; i += 256) cnt[i] = 0;
    __syncthreads();
    int lo = blockIdx.x * CHUNK_A;
    int hi = lo + CHUNK_A;
    if (hi > nE) hi = nE;
    for (int e = lo + t; e < hi; e += 256)
        atomicAdd(&cnt[dst[e] >> BSHIFT], 1);
    __syncthreads();
    for (int i = t; i < NBUCK; i += 256)
        if (cnt[i]) atomicAdd(&bcnt[i], cnt[i]);
}

__global__ __launch_bounds__(128) void bucket_scan(
    const int* __restrict__ bcnt, int* __restrict__ bucket_base,
    int* __restrict__ cursor, int nE)
{
    int tid = threadIdx.x;  // NBUCK <= 128
    int v = tid < NBUCK ? bcnt[tid] : 0;
    int lane = tid & 63, w = tid >> 6;
    int incl = wave_incl_scan(v);
    __shared__ int ws[2];
    if (lane == 63) ws[w] = incl;
    __syncthreads();
    int off = (w == 1) ? ws[0] : 0;
    int excl = off + incl - v;
    if (tid < NBUCK) {
        bucket_base[tid] = excl;
        cursor[tid] = excl;
    }
    if (tid == 0) bucket_base[NBUCK] = nE;
}

__global__ __launch_bounds__(256) void bucket_pass(
    const int* __restrict__ src, const int* __restrict__ dst,
    int* __restrict__ cursor, int2* __restrict__ ebuf, int nE)
{
    __shared__ int cnt[NBUCK];
    __shared__ int base[NBUCK];
    int t = threadIdx.x;
    for (int i = t; i < NBUCK; i += 256) cnt[i] = 0;
    __syncthreads();

    int lo = blockIdx.x * CHUNK_A;
    int hi = lo + CHUNK_A;
    if (hi > nE) hi = nE;

    for (int e = lo + t; e < hi; e += 256)
        atomicAdd(&cnt[dst[e] >> BSHIFT], 1);
    __syncthreads();

    for (int i = t; i < NBUCK; i += 256)
        base[i] = cnt[i] ? atomicAdd(&cursor[i], cnt[i]) : 0;
    __syncthreads();
    for (int i = t; i < NBUCK; i += 256) cnt[i] = 0;
    __syncthreads();

    for (int e = lo + t; e < hi; e += 256) {
        int d = dst[e];
        int b = d >> BSHIFT;
        int p = base[b] + atomicAdd(&cnt[b], 1);
        ebuf[p] = make_int2(src[e], d);
    }
}

__global__ __launch_bounds__(256) void bucket_build(
    const int* __restrict__ bucket_base, const int2* __restrict__ ebuf,
    int* __restrict__ row_start, int* __restrict__ ssrc)
{
    int b = blockIdx.x;
    int nlo = b << BSHIFT;
    int nhi = nlo + BSIZE;
    if (nhi > N_NODES_C) nhi = N_NODES_C;
    int nloc = nhi - nlo;

    __shared__ int degl[BSIZE];
    __shared__ int posl[BSIZE];
    __shared__ int ws[4];
    int t = threadIdx.x;

    for (int i = t; i < BSIZE; i += 256) degl[i] = 0;
    __syncthreads();

    int lo = bucket_base[b];
    int hi = bucket_base[b + 1];
    for (int e = lo + t; e < hi; e += 256)
        atomicAdd(&degl[ebuf[e].y - nlo], 1);
    __syncthreads();

    int base4 = t * 4;
    int v0 = degl[base4 + 0], v1 = degl[base4 + 1];
    int v2 = degl[base4 + 2], v3 = degl[base4 + 3];
    int lsum = v0 + v1 + v2 + v3;
    int incl = wave_incl_scan(lsum);
    int lane = t & 63, w = t >> 6;
    if (lane == 63) ws[w] = incl;
    __syncthreads();
    int woff = 0;
    for (int i = 0; i < w; ++i) woff += ws[i];
    int pp = lo + woff + incl - lsum;
    if (base4 + 0 < nloc) { row_start[nlo + base4 + 0] = pp; posl[base4 + 0] = pp; } pp += v0;
    if (base4 + 1 < nloc) { row_start[nlo + base4 + 1] = pp; posl[base4 + 1] = pp; } pp += v1;
    if (base4 + 2 < nloc) { row_start[nlo + base4 + 2] = pp; posl[base4 + 2] = pp; } pp += v2;
    if (base4 + 3 < nloc) { row_start[nlo + base4 + 3] = pp; posl[base4 + 3] = pp; } pp += v3;
    if (t == 0 && nhi == N_NODES_C) row_start[N_NODES_C] = hi;
    __syncthreads();

    for (int e = lo + t; e < hi; e += 256) {
        int2 sd = ebuf[e];
        int q = atomicAdd(&posl[sd.y - nlo], 1);
        ssrc[q] = sd.x;
    }
}

// ---------------------------------------------------------------------------
// Gather-sum v2: 4-deep software pipeline. Latency-bound before (VALUBusy
// 13%, only ~2 gathers in flight/thread); batch 4 ssrc loads then 4
// independent float4 gathers before accumulating.
// ---------------------------------------------------------------------------
template<int D>
__global__ __launch_bounds__(256) void gather_agg(
    const float* __restrict__ x, const int* __restrict__ row_start,
    const int* __restrict__ ssrc, float* __restrict__ agg, int nNodes)
{
    const int L = D / 4;
    const int NPB = 256 / L;
    int local = threadIdx.x / L;
    int lane  = threadIdx.x % L;
    int n = blockIdx.x * NPB + local;
    if (n >= nNodes) return;
    int beg = row_start[n], end = row_start[n + 1];
    float4 acc = make_float4(0.f, 0.f, 0.f, 0.f);
    int e = beg;
#pragma unroll 1
    for (; e + 3 < end; e += 4) {
        int s0 = ssrc[e], s1 = ssrc[e + 1], s2 = ssrc[e + 2], s3 = ssrc[e + 3];
        float4 v0 = *reinterpret_cast<const float4*>(x + (size_t)s0 * D + lane * 4);
        float4 v1 = *reinterpret_cast<const float4*>(x + (size_t)s1 * D + lane * 4);
        float4 v2 = *reinterpret_cast<const float4*>(x + (size_t)s2 * D + lane * 4);
        float4 v3 = *reinterpret_cast<const float4*>(x + (size_t)s3 * D + lane * 4);
        acc.x += (v0.x + v1.x) + (v2.x + v3.x);
        acc.y += (v0.y + v1.y) + (v2.y + v3.y);
        acc.z += (v0.z + v1.z) + (v2.z + v3.z);
        acc.w += (v0.w + v1.w) + (v2.w + v3.w);
    }
    if (e + 1 < end) {
        int s0 = ssrc[e], s1 = ssrc[e + 1];
        float4 v0 = *reinterpret_cast<const float4*>(x + (size_t)s0 * D + lane * 4);
        float4 v1 = *reinterpret_cast<const float4*>(x + (size_t)s1 * D + lane * 4);
        acc.x += v0.x + v1.x; acc.y += v0.y + v1.y;
        acc.z += v0.z + v1.z; acc.w += v0.w + v1.w;
        e += 2;
    }
    if (e < end) {
        int s0 = ssrc[e];
        float4 v0 = *reinterpret_cast<const float4*>(x + (size_t)s0 * D + lane * 4);
        acc.x += v0.x; acc.y += v0.y; acc.z += v0.z; acc.w += v0.w;
    }
    *reinterpret_cast<float4*>(agg + (size_t)n * D + lane * 4) = acc;
}

// ---------------------------------------------------------------------------
// Node transform v4 (measured-good): LDS-staged inputs, 2 nodes x 8 outputs
// per thread, rolled k-loop (full unroll spilled at 256 VGPRs).
// ---------------------------------------------------------------------------
template<int DIN, int DOUT>
__global__ __launch_bounds__(256) void transform_v4(
    const float* __restrict__ agg, const float* __restrict__ xin,
    const float* __restrict__ w_rel, const float* __restrict__ bias,
    const float* __restrict__ w_root, float* __restrict__ out, int nNodes)
{
    constexpr int JB = 8;
    constexpr int TPN = DOUT / JB;
    constexpr int SLOTS = 256 / TPN;
    constexpr int NT = 2;
    constexpr int NPB = SLOTS * NT;
    constexpr int PITCH = DIN + 4;

    __shared__ float wr[DIN * DOUT];
    __shared__ float wt[DIN * DOUT];
    __shared__ float a_s[NPB * PITCH];
    __shared__ float x_s[NPB * PITCH];

    {
        const float4* wr4 = reinterpret_cast<const float4*>(w_rel);
        const float4* wt4 = reinterpret_cast<const float4*>(w_root);
        float4* wrd = reinterpret_cast<float4*>(wr);
        float4* wtd = reinterpret_cast<float4*>(wt);
        for (int i = threadIdx.x; i < DIN * DOUT / 4; i += 256) {
            wrd[i] = wr4[i];
            wtd[i] = wt4[i];
        }
    }

    int n0 = blockIdx.x * NPB;
    constexpr int NV = NPB * DIN / 4;
    for (int v = threadIdx.x; v < NV; v += 256) {
        int row  = v / (DIN / 4);
        int col4 = v % (DIN / 4);
        int n = n0 + row;
        float4 a = make_float4(0.f, 0.f, 0.f, 0.f);
        float4 xx = a;
        if (n < nNodes) {
            a  = *reinterpret_cast<const float4*>(agg + (size_t)n * DIN + col4 * 4);
            xx = *reinterpret_cast<const float4*>(xin + (size_t)n * DIN + col4 * 4);
        }
        *reinterpret_cast<float4*>(&a_s[row * PITCH + col4 * 4]) = a;
        *reinterpret_cast<float4*>(&x_s[row * PITCH + col4 * 4]) = xx;
    }
    __syncthreads();

    int slot = threadIdx.x / TPN;
    int j0 = (threadIdx.x % TPN) * JB;

    float4 biasLo = *reinterpret_cast<const float4*>(bias + j0);
    float4 biasHi = *reinterpret_cast<const float4*>(bias + j0 + 4);
    float4 accA0 = biasLo, accA1 = biasHi;
    float4 accB0 = biasLo, accB1 = biasHi;

    const float* arA = &a_s[slot * PITCH];
    const float* xrA = &x_s[slot * PITCH];
    const float* arB = arA + SLOTS * PITCH;
    const float* xrB = xrA + SLOTS * PITCH;

#pragma unroll 2
    for (int k = 0; k < DIN; ++k) {
        float aA = arA[k], xA = xrA[k];
        float aB = arB[k], xB = xrB[k];
        float4 w0 = *reinterpret_cast<const float4*>(&wr[k * DOUT + j0]);
        float4 w1 = *reinterpret_cast<const float4*>(&wr[k * DOUT + j0 + 4]);
        float4 t0 = *reinterpret_cast<const float4*>(&wt[k * DOUT + j0]);
        float4 t1 = *reinterpret_cast<const float4*>(&wt[k * DOUT + j0 + 4]);
        accA0.x += aA * w0.x + xA * t0.x;
        accA0.y += aA * w0.y + xA * t0.y;
        accA0.z += aA * w0.z + xA * t0.z;
        accA0.w += aA * w0.w + xA * t0.w;
        accA1.x += aA * w1.x + xA * t1.x;
        accA1.y += aA * w1.y + xA * t1.y;
        accA1.z += aA * w1.z + xA * t1.z;
        accA1.w += aA * w1.w + xA * t1.w;
        accB0.x += aB * w0.x + xB * t0.x;
        accB0.y += aB * w0.y + xB * t0.y;
        accB0.z += aB * w0.z + xB * t0.z;
        accB0.w += aB * w0.w + xB * t0.w;
        accB1.x += aB * w1.x + xB * t1.x;
        accB1.y += aB * w1.y + xB * t1.y;
        accB1.z += aB * w1.z + xB * t1.z;
        accB1.w += aB * w1.w + xB * t1.w;
    }

    int nA = n0 + slot;
    int nB = nA + SLOTS;
    if (nA < nNodes) {
        float4 o0, o1;
        o0.x = elu_f(accA0.x); o0.y = elu_f(accA0.y); o0.z = elu_f(accA0.z); o0.w = elu_f(accA0.w);
        o1.x = elu_f(accA1.x); o1.y = elu_f(accA1.y); o1.z = elu_f(accA1.z); o1.w = elu_f(accA1.w);
        *reinterpret_cast<float4*>(out + (size_t)nA * DOUT + j0)     = o0;
        *reinterpret_cast<float4*>(out + (size_t)nA * DOUT + j0 + 4) = o1;
    }
    if (nB < nNodes) {
        float4 o0, o1;
        o0.x = elu_f(accB0.x); o0.y = elu_f(accB0.y); o0.z = elu_f(accB0.z); o0.w = elu_f(accB0.w);
        o1.x = elu_f(accB1.x); o1.y = elu_f(accB1.y); o1.z = elu_f(accB1.z); o1.w = elu_f(accB1.w);
        *reinterpret_cast<float4*>(out + (size_t)nB * DOUT + j0)     = o0;
        *reinterpret_cast<float4*>(out + (size_t)nB * DOUT + j0 + 4) = o1;
    }
}

// ---------------------------------------------------------------------------
// Mean-pool v2 (measured-good): 256 threads = (sub 0..3, feat 0..63).
// ---------------------------------------------------------------------------
#define POOL_CHUNK 256
__global__ __launch_bounds__(256) void pool_kernel2(
    const float* __restrict__ h, const int* __restrict__ batch,
    float* __restrict__ sums, float* __restrict__ cnts, int nNodes)
{
    int t = threadIdx.x;
    int j = t & 63;
    int sub = t >> 6;
    int start = blockIdx.x * POOL_CHUNK + sub;
    int end = blockIdx.x * POOL_CHUNK + POOL_CHUNK;
    if (end > nNodes) end = nNodes;
    if (start >= end) return;

    int g = batch[start];
    float acc = 0.f;
    float c = 0.f;
    for (int n = start; n < end; n += 4) {
        int gn = batch[n];
        if (gn != g) {
            unsafeAtomicAdd(&sums[(size_t)g * 64 + j], acc);
            if (j == 0) unsafeAtomicAdd(&cnts[g], c);
            acc = 0.f; c = 0.f; g = gn;
        }
        acc += h[(size_t)n * 64 + j];
        c += 1.f;
    }
    unsafeAtomicAdd(&sums[(size_t)g * 64 + j], acc);
    if (j == 0) unsafeAtomicAdd(&cnts[g], c);
}

// ---------------------------------------------------------------------------
// MLP head + log_softmax: one 64-thread block per graph.
// ---------------------------------------------------------------------------
__global__ __launch_bounds__(64) void mlp_kernel(
    const float* __restrict__ sums, const float* __restrict__ cnts,
    const float* __restrict__ fw1, const float* __restrict__ fb1,
    const float* __restrict__ fw2, const float* __restrict__ fb2,
    const float* __restrict__ fw3, const float* __restrict__ fb3,
    float* __restrict__ out)
{
    int g = blockIdx.x;
    int j = threadIdx.x;
    __shared__ float p[64];
    __shared__ float z1[64];
    __shared__ float z2[32];
    __shared__ float z3[10];
    __shared__ float lse;

    float c = fmaxf(cnts[g], 1.f);
    p[j] = sums[(size_t)g * 64 + j] / c;
    __syncthreads();

    float a = fb1[j];
#pragma unroll
    for (int k = 0; k < 64; ++k) a += p[k] * fw1[k * 64 + j];
    z1[j] = elu_f(a);
    __syncthreads();

    if (j < 32) {
        float a2 = fb2[j];
#pragma unroll
        for (int k = 0; k < 64; ++k) a2 += z1[k] * fw2[k * 32 + j];
        z2[j] = elu_f(a2);
    }
    __syncthreads();

    if (j < 10) {
        float a3 = fb3[j];
#pragma unroll
        for (int k = 0; k < 32; ++k) a3 += z2[k] * fw3[k * 10 + j];
        z3[j] = a3;
    }
    __syncthreads();

    if (j == 0) {
        float m = -1e30f;
        for (int i = 0; i < 10; ++i) m = fmaxf(m, z3[i]);
        float s = 0.f;
        for (int i = 0; i < 10; ++i) s += expf(z3[i] - m);
        lse = logf(s) + m;
    }
    __syncthreads();

    if (j < 10) out[(size_t)g * 10 + j] = z3[j] - lse;
}

// ---------------------------------------------------------------------------
extern "C" void kernel_launch(void* const* d_in, const int* in_sizes, int n_in,
                              void* d_out, int out_size, void* d_ws, size_t ws_size,
                              hipStream_t stream)
{
    const float* x       = (const float*)d_in[0];
    const int*   ei      = (const int*)  d_in[1];
    const int*   batch   = (const int*)  d_in[2];
    const float* w1_rel  = (const float*)d_in[3];
    const float* b1      = (const float*)d_in[4];
    const float* w1_root = (const float*)d_in[5];
    const float* w2_rel  = (const float*)d_in[6];
    const float* b2      = (const float*)d_in[7];
    const float* w2_root = (const float*)d_in[8];
    const float* w3_rel  = (const float*)d_in[9];
    const float* b3      = (const float*)d_in[10];
    const float* w3_root = (const float*)d_in[11];
    const float* fw1     = (const float*)d_in[12];
    const float* fb1     = (const float*)d_in[13];
    const float* fw2     = (const float*)d_in[14];
    const float* fb2     = (const float*)d_in[15];
    const float* fw3     = (const float*)d_in[16];
    const float* fb3     = (const float*)d_in[17];
    float* out = (float*)d_out;

    const int* src = ei;
    const int* dst = ei + N_EDGES_C;

    // workspace layout
    float* agg  = (float*)d_ws;                          // N*64 f
    float* hB   = agg  + (size_t)N_NODES_C * 64;         // N*64 f
    float* hC   = hB   + (size_t)N_NODES_C * 64;         // N*64 f
    float* sums = hC   + (size_t)N_NODES_C * 64;         // 512*64 f
    float* cnts = sums + (size_t)N_GRAPHS_C * 64;        // 512 f
    int*   row_start = (int*)(cnts + N_GRAPHS_C);        // N+1 int
    int*   bcnt = row_start + N_NODES_C + 1;             // NBUCK int
    int*   bucket_base = bcnt + NBUCK;                   // NBUCK+1 int
    int*   cursor = bucket_base + NBUCK + 1;             // NBUCK int
    int*   ssrc = cursor + NBUCK;                        // nE int
    int2*  ebuf = (int2*)hC;  // aliased: CSR build done before hC written

    // ---- bucketed CSR build ----
    hipMemsetAsync(bcnt, 0, NBUCK * sizeof(int), stream);
    bucket_count<<<(N_EDGES_C + CHUNK_A - 1) / CHUNK_A, 256, 0, stream>>>(
        dst, bcnt, N_EDGES_C);
    bucket_scan<<<1, 128, 0, stream>>>(bcnt, bucket_base, cursor, N_EDGES_C);
    bucket_pass<<<(N_EDGES_C + CHUNK_A - 1) / CHUNK_A, 256, 0, stream>>>(
        src, dst, cursor, ebuf, N_EDGES_C);
    bucket_build<<<NBUCK, 256, 0, stream>>>(bucket_base, ebuf, row_start, ssrc);

    // ---- layer 1: 32 -> 32, x -> hB ----
    gather_agg<32><<<(N_NODES_C + 31) / 32, 256, 0, stream>>>(x, row_start, ssrc, agg, N_NODES_C);
    transform_v4<32, 32><<<(N_NODES_C + 127) / 128, 256, 0, stream>>>(
        agg, x, w1_rel, b1, w1_root, hB, N_NODES_C);

    // ---- layer 2: 32 -> 64, hB -> hC ----
    gather_agg<32><<<(N_NODES_C + 31) / 32, 256, 0, stream>>>(hB, row_start, ssrc, agg, N_NODES_C);
    transform_v4<32, 64><<<(N_NODES_C + 63) / 64, 256, 0, stream>>>(
        agg, hB, w2_rel, b2, w2_root, hC, N_NODES_C);

    // ---- layer 3: 64 -> 64, hC -> hB ----
    gather_agg<64><<<(N_NODES_C + 15) / 16, 256, 0, stream>>>(hC, row_start, ssrc, agg, N_NODES_C);
    transform_v4<64, 64><<<(N_NODES_C + 63) / 64, 256, 0, stream>>>(
        agg, hC, w3_rel, b3, w3_root, hB, N_NODES_C);

    // ---- mean pool ----
    hipMemsetAsync(sums, 0, ((size_t)N_GRAPHS_C * 64 + N_GRAPHS_C) * sizeof(float), stream);
    pool_kernel2<<<(N_NODES_C + POOL_CHUNK - 1) / POOL_CHUNK, 256, 0, stream>>>(
        hB, batch, sums, cnts, N_NODES_C);

    // ---- MLP head + log_softmax ----
    mlp_kernel<<<N_GRAPHS_C, 64, 0, stream>>>(
        sums, cnts, fw1, fb1, fw2, fb2, fw3, fb3, out);
}

// Round 11
// 293.413 us; speedup vs baseline: 1.7499x; 1.1299x over previous
//
#include <hip/hip_runtime.h>
#include <hip/hip_bf16.h>
#include <math.h>

#define N_NODES_C 100000
#define N_EDGES_C 1600000
#define N_GRAPHS_C 512
#define BSHIFT 10
#define BSIZE (1 << BSHIFT)
#define NBUCK ((N_NODES_C + BSIZE - 1) >> BSHIFT)   // 98
#define CHUNK_A 8192

typedef unsigned int  uint_t;
typedef unsigned short ushort_t;

__device__ __forceinline__ float elu_f(float x) { return x > 0.f ? x : expm1f(x); }

// bf16 helpers (RNE pack, shift unpack). Finite values only.
__device__ __forceinline__ ushort_t f2bf(float f) {
    uint_t u = __float_as_uint(f);
    u += 0x7FFFu + ((u >> 16) & 1u);
    return (ushort_t)(u >> 16);
}
__device__ __forceinline__ uint_t pack2bf(float lo, float hi) {
    return (uint_t)f2bf(lo) | ((uint_t)f2bf(hi) << 16);
}
__device__ __forceinline__ float bf_lo(uint_t u) { return __uint_as_float(u << 16); }
__device__ __forceinline__ float bf_hi(uint_t u) { return __uint_as_float(u & 0xFFFF0000u); }

__device__ __forceinline__ int wave_incl_scan(int v) {
    int lane = threadIdx.x & 63;
#pragma unroll
    for (int o = 1; o < 64; o <<= 1) {
        int t = __shfl_up(v, o);
        if (lane >= o) v += t;
    }
    return v;
}

// ---------------------------------------------------------------------------
// f32 -> bf16 conversion of the input features (8 elems/thread).
// ---------------------------------------------------------------------------
__global__ __launch_bounds__(256) void cvt_bf16(
    const float* __restrict__ in, uint_t* __restrict__ out, int n8)
{
    int i = blockIdx.x * 256 + threadIdx.x;
    if (i >= n8) return;
    const float4* p = reinterpret_cast<const float4*>(in) + 2 * i;
    float4 a = p[0], b = p[1];
    uint4 o;
    o.x = pack2bf(a.x, a.y); o.y = pack2bf(a.z, a.w);
    o.z = pack2bf(b.x, b.y); o.w = pack2bf(b.z, b.w);
    reinterpret_cast<uint4*>(out)[i] = o;
}

// ---------------------------------------------------------------------------
// Bucketed CSR build (round-9 measured-good), ebuf packed to ONE int:
// (local_dst:10b << 17) | src:17b  (100000 < 2^17).
// ---------------------------------------------------------------------------
__global__ __launch_bounds__(256) void bucket_count(
    const int* __restrict__ dst, int* __restrict__ bcnt, int nE)
{
    __shared__ int cnt[NBUCK];
    int t = threadIdx.x;
    for (int i = t; i < NBUCK; i += 256) cnt[i] = 0;
    __syncthreads();
    int lo = blockIdx.x * CHUNK_A;
    int hi = lo + CHUNK_A;
    if (hi > nE) hi = nE;
    for (int e = lo + t; e < hi; e += 256)
        atomicAdd(&cnt[dst[e] >> BSHIFT], 1);
    __syncthreads();
    for (int i = t; i < NBUCK; i += 256)
        if (cnt[i]) atomicAdd(&bcnt[i], cnt[i]);
}

__global__ __launch_bounds__(128) void bucket_scan(
    const int* __restrict__ bcnt, int* __restrict__ bucket_base,
    int* __restrict__ cursor, int nE)
{
    int tid = threadIdx.x;  // NBUCK <= 128
    int v = tid < NBUCK ? bcnt[tid] : 0;
    int lane = tid & 63, w = tid >> 6;
    int incl = wave_incl_scan(v);
    __shared__ int ws[2];
    if (lane == 63) ws[w] = incl;
    __syncthreads();
    int off = (w == 1) ? ws[0] : 0;
    int excl = off + incl - v;
    if (tid < NBUCK) {
        bucket_base[tid] = excl;
        cursor[tid] = excl;
    }
    if (tid == 0) bucket_base[NBUCK] = nE;
}

__global__ __launch_bounds__(256) void bucket_pass(
    const int* __restrict__ src, const int* __restrict__ dst,
    int* __restrict__ cursor, int* __restrict__ ebuf, int nE)
{
    __shared__ int cnt[NBUCK];
    __shared__ int base[NBUCK];
    int t = threadIdx.x;
    for (int i = t; i < NBUCK; i += 256) cnt[i] = 0;
    __syncthreads();

    int lo = blockIdx.x * CHUNK_A;
    int hi = lo + CHUNK_A;
    if (hi > nE) hi = nE;

    for (int e = lo + t; e < hi; e += 256)
        atomicAdd(&cnt[dst[e] >> BSHIFT], 1);
    __syncthreads();

    for (int i = t; i < NBUCK; i += 256)
        base[i] = cnt[i] ? atomicAdd(&cursor[i], cnt[i]) : 0;
    __syncthreads();
    for (int i = t; i < NBUCK; i += 256) cnt[i] = 0;
    __syncthreads();

    for (int e = lo + t; e < hi; e += 256) {
        int d = dst[e];
        int b = d >> BSHIFT;
        int p = base[b] + atomicAdd(&cnt[b], 1);
        ebuf[p] = ((d & (BSIZE - 1)) << 17) | src[e];
    }
}

__global__ __launch_bounds__(256) void bucket_build(
    const int* __restrict__ bucket_base, const int* __restrict__ ebuf,
    int* __restrict__ row_start, int* __restrict__ ssrc)
{
    int b = blockIdx.x;
    int nlo = b << BSHIFT;
    int nhi = nlo + BSIZE;
    if (nhi > N_NODES_C) nhi = N_NODES_C;
    int nloc = nhi - nlo;

    __shared__ int degl[BSIZE];
    __shared__ int posl[BSIZE];
    __shared__ int ws[4];
    int t = threadIdx.x;

    for (int i = t; i < BSIZE; i += 256) degl[i] = 0;
    __syncthreads();

    int lo = bucket_base[b];
    int hi = bucket_base[b + 1];
    for (int e = lo + t; e < hi; e += 256)
        atomicAdd(&degl[ebuf[e] >> 17], 1);
    __syncthreads();

    int base4 = t * 4;
    int v0 = degl[base4 + 0], v1 = degl[base4 + 1];
    int v2 = degl[base4 + 2], v3 = degl[base4 + 3];
    int lsum = v0 + v1 + v2 + v3;
    int incl = wave_incl_scan(lsum);
    int lane = t & 63, w = t >> 6;
    if (lane == 63) ws[w] = incl;
    __syncthreads();
    int woff = 0;
    for (int i = 0; i < w; ++i) woff += ws[i];
    int pp = lo + woff + incl - lsum;
    if (base4 + 0 < nloc) { row_start[nlo + base4 + 0] = pp; posl[base4 + 0] = pp; } pp += v0;
    if (base4 + 1 < nloc) { row_start[nlo + base4 + 1] = pp; posl[base4 + 1] = pp; } pp += v1;
    if (base4 + 2 < nloc) { row_start[nlo + base4 + 2] = pp; posl[base4 + 2] = pp; } pp += v2;
    if (base4 + 3 < nloc) { row_start[nlo + base4 + 3] = pp; posl[base4 + 3] = pp; } pp += v3;
    if (t == 0 && nhi == N_NODES_C) row_start[N_NODES_C] = hi;
    __syncthreads();

    for (int e = lo + t; e < hi; e += 256) {
        int v = ebuf[e];
        int q = atomicAdd(&posl[v >> 17], 1);
        ssrc[q] = v & 0x1FFFF;
    }
}

// ---------------------------------------------------------------------------
// Gather-sum over bf16 rows, f32 accumulation. D/8 lanes per node, each lane
// loads 16B = 8 bf16 columns. D=32 row = 64B = one cache line.
// ---------------------------------------------------------------------------
template<int D>
__global__ __launch_bounds__(256) void gather_bf(
    const ushort_t* __restrict__ xb, const int* __restrict__ row_start,
    const int* __restrict__ ssrc, float* __restrict__ agg, int nNodes)
{
    const int L = D / 8;        // lanes per node
    const int NPB = 256 / L;
    int local = threadIdx.x / L;
    int lane  = threadIdx.x % L;
    int n = blockIdx.x * NPB + local;
    if (n >= nNodes) return;
    int beg = row_start[n], end = row_start[n + 1];
    float4 accA = make_float4(0.f, 0.f, 0.f, 0.f);
    float4 accB = accA;
    int e = beg;
#pragma unroll 1
    for (; e + 1 < end; e += 2) {
        int s0 = ssrc[e], s1 = ssrc[e + 1];
        uint4 u0 = reinterpret_cast<const uint4*>(xb + (size_t)s0 * D)[lane];
        uint4 u1 = reinterpret_cast<const uint4*>(xb + (size_t)s1 * D)[lane];
        accA.x += bf_lo(u0.x) + bf_lo(u1.x);
        accA.y += bf_hi(u0.x) + bf_hi(u1.x);
        accA.z += bf_lo(u0.y) + bf_lo(u1.y);
        accA.w += bf_hi(u0.y) + bf_hi(u1.y);
        accB.x += bf_lo(u0.z) + bf_lo(u1.z);
        accB.y += bf_hi(u0.z) + bf_hi(u1.z);
        accB.z += bf_lo(u0.w) + bf_lo(u1.w);
        accB.w += bf_hi(u0.w) + bf_hi(u1.w);
    }
    if (e < end) {
        int s0 = ssrc[e];
        uint4 u0 = reinterpret_cast<const uint4*>(xb + (size_t)s0 * D)[lane];
        accA.x += bf_lo(u0.x); accA.y += bf_hi(u0.x);
        accA.z += bf_lo(u0.y); accA.w += bf_hi(u0.y);
        accB.x += bf_lo(u0.z); accB.y += bf_hi(u0.z);
        accB.z += bf_lo(u0.w); accB.w += bf_hi(u0.w);
    }
    float* outp = agg + (size_t)n * D + lane * 8;
    *reinterpret_cast<float4*>(outp)     = accA;
    *reinterpret_cast<float4*>(outp + 4) = accB;
}

// ---------------------------------------------------------------------------
// Node transform: agg f32 + xin bf16 -> out bf16. LDS-staged, 2 nodes x
// 8 outputs per thread, rolled k-loop (full unroll spilled; rounds 3/4).
// ---------------------------------------------------------------------------
template<int DIN, int DOUT>
__global__ __launch_bounds__(256) void transform_bf(
    const float* __restrict__ agg, const ushort_t* __restrict__ xin,
    const float* __restrict__ w_rel, const float* __restrict__ bias,
    const float* __restrict__ w_root, ushort_t* __restrict__ out, int nNodes)
{
    constexpr int JB = 8;
    constexpr int TPN = DOUT / JB;
    constexpr int SLOTS = 256 / TPN;
    constexpr int NT = 2;
    constexpr int NPB = SLOTS * NT;
    constexpr int PITCH = DIN + 4;

    __shared__ float wr[DIN * DOUT];
    __shared__ float wt[DIN * DOUT];
    __shared__ float a_s[NPB * PITCH];
    __shared__ float x_s[NPB * PITCH];

    {
        const float4* wr4 = reinterpret_cast<const float4*>(w_rel);
        const float4* wt4 = reinterpret_cast<const float4*>(w_root);
        float4* wrd = reinterpret_cast<float4*>(wr);
        float4* wtd = reinterpret_cast<float4*>(wt);
        for (int i = threadIdx.x; i < DIN * DOUT / 4; i += 256) {
            wrd[i] = wr4[i];
            wtd[i] = wt4[i];
        }
    }

    int n0 = blockIdx.x * NPB;
    // a_s from f32 agg
    constexpr int NV = NPB * DIN / 4;
    for (int v = threadIdx.x; v < NV; v += 256) {
        int row  = v / (DIN / 4);
        int col4 = v % (DIN / 4);
        int n = n0 + row;
        float4 a = make_float4(0.f, 0.f, 0.f, 0.f);
        if (n < nNodes)
            a = *reinterpret_cast<const float4*>(agg + (size_t)n * DIN + col4 * 4);
        *reinterpret_cast<float4*>(&a_s[row * PITCH + col4 * 4]) = a;
    }
    // x_s from bf16 xin (8 cols per item)
    constexpr int NX = NPB * DIN / 8;
    for (int v = threadIdx.x; v < NX; v += 256) {
        int row  = v / (DIN / 8);
        int col8 = v % (DIN / 8);
        int n = n0 + row;
        uint4 u = make_uint4(0, 0, 0, 0);
        if (n < nNodes)
            u = reinterpret_cast<const uint4*>(xin + (size_t)n * DIN)[col8];
        float* xp = &x_s[row * PITCH + col8 * 8];
        xp[0] = bf_lo(u.x); xp[1] = bf_hi(u.x);
        xp[2] = bf_lo(u.y); xp[3] = bf_hi(u.y);
        xp[4] = bf_lo(u.z); xp[5] = bf_hi(u.z);
        xp[6] = bf_lo(u.w); xp[7] = bf_hi(u.w);
    }
    __syncthreads();

    int slot = threadIdx.x / TPN;
    int j0 = (threadIdx.x % TPN) * JB;

    float4 biasLo = *reinterpret_cast<const float4*>(bias + j0);
    float4 biasHi = *reinterpret_cast<const float4*>(bias + j0 + 4);
    float4 accA0 = biasLo, accA1 = biasHi;
    float4 accB0 = biasLo, accB1 = biasHi;

    const float* arA = &a_s[slot * PITCH];
    const float* xrA = &x_s[slot * PITCH];
    const float* arB = arA + SLOTS * PITCH;
    const float* xrB = xrA + SLOTS * PITCH;

#pragma unroll 2
    for (int k = 0; k < DIN; ++k) {
        float aA = arA[k], xA = xrA[k];
        float aB = arB[k], xB = xrB[k];
        float4 w0 = *reinterpret_cast<const float4*>(&wr[k * DOUT + j0]);
        float4 w1 = *reinterpret_cast<const float4*>(&wr[k * DOUT + j0 + 4]);
        float4 t0 = *reinterpret_cast<const float4*>(&wt[k * DOUT + j0]);
        float4 t1 = *reinterpret_cast<const float4*>(&wt[k * DOUT + j0 + 4]);
        accA0.x += aA * w0.x + xA * t0.x;
        accA0.y += aA * w0.y + xA * t0.y;
        accA0.z += aA * w0.z + xA * t0.z;
        accA0.w += aA * w0.w + xA * t0.w;
        accA1.x += aA * w1.x + xA * t1.x;
        accA1.y += aA * w1.y + xA * t1.y;
        accA1.z += aA * w1.z + xA * t1.z;
        accA1.w += aA * w1.w + xA * t1.w;
        accB0.x += aB * w0.x + xB * t0.x;
        accB0.y += aB * w0.y + xB * t0.y;
        accB0.z += aB * w0.z + xB * t0.z;
        accB0.w += aB * w0.w + xB * t0.w;
        accB1.x += aB * w1.x + xB * t1.x;
        accB1.y += aB * w1.y + xB * t1.y;
        accB1.z += aB * w1.z + xB * t1.z;
        accB1.w += aB * w1.w + xB * t1.w;
    }

    int nA = n0 + slot;
    int nB = nA + SLOTS;
    if (nA < nNodes) {
        uint4 ob;
        ob.x = pack2bf(elu_f(accA0.x), elu_f(accA0.y));
        ob.y = pack2bf(elu_f(accA0.z), elu_f(accA0.w));
        ob.z = pack2bf(elu_f(accA1.x), elu_f(accA1.y));
        ob.w = pack2bf(elu_f(accA1.z), elu_f(accA1.w));
        *reinterpret_cast<uint4*>(out + (size_t)nA * DOUT + j0) = ob;
    }
    if (nB < nNodes) {
        uint4 ob;
        ob.x = pack2bf(elu_f(accB0.x), elu_f(accB0.y));
        ob.y = pack2bf(elu_f(accB0.z), elu_f(accB0.w));
        ob.z = pack2bf(elu_f(accB1.x), elu_f(accB1.y));
        ob.w = pack2bf(elu_f(accB1.z), elu_f(accB1.w));
        *reinterpret_cast<uint4*>(out + (size_t)nB * DOUT + j0) = ob;
    }
}

// ---------------------------------------------------------------------------
// Mean-pool over sorted batch, bf16 input, f32 sums.
// ---------------------------------------------------------------------------
#define POOL_CHUNK 256
__global__ __launch_bounds__(256) void pool_bf(
    const ushort_t* __restrict__ h, const int* __restrict__ batch,
    float* __restrict__ sums, float* __restrict__ cnts, int nNodes)
{
    int t = threadIdx.x;
    int j = t & 63;
    int sub = t >> 6;
    int start = blockIdx.x * POOL_CHUNK + sub;
    int end = blockIdx.x * POOL_CHUNK + POOL_CHUNK;
    if (end > nNodes) end = nNodes;
    if (start >= end) return;

    int g = batch[start];
    float acc = 0.f;
    float c = 0.f;
    for (int n = start; n < end; n += 4) {
        int gn = batch[n];
        if (gn != g) {
            unsafeAtomicAdd(&sums[(size_t)g * 64 + j], acc);
            if (j == 0) unsafeAtomicAdd(&cnts[g], c);
            acc = 0.f; c = 0.f; g = gn;
        }
        acc += __uint_as_float(((uint_t)h[(size_t)n * 64 + j]) << 16);
        c += 1.f;
    }
    unsafeAtomicAdd(&sums[(size_t)g * 64 + j], acc);
    if (j == 0) unsafeAtomicAdd(&cnts[g], c);
}

// ---------------------------------------------------------------------------
// MLP head + log_softmax: one 64-thread block per graph.
// ---------------------------------------------------------------------------
__global__ __launch_bounds__(64) void mlp_kernel(
    const float* __restrict__ sums, const float* __restrict__ cnts,
    const float* __restrict__ fw1, const float* __restrict__ fb1,
    const float* __restrict__ fw2, const float* __restrict__ fb2,
    const float* __restrict__ fw3, const float* __restrict__ fb3,
    float* __restrict__ out)
{
    int g = blockIdx.x;
    int j = threadIdx.x;
    __shared__ float p[64];
    __shared__ float z1[64];
    __shared__ float z2[32];
    __shared__ float z3[10];
    __shared__ float lse;

    float c = fmaxf(cnts[g], 1.f);
    p[j] = sums[(size_t)g * 64 + j] / c;
    __syncthreads();

    float a = fb1[j];
#pragma unroll
    for (int k = 0; k < 64; ++k) a += p[k] * fw1[k * 64 + j];
    z1[j] = elu_f(a);
    __syncthreads();

    if (j < 32) {
        float a2 = fb2[j];
#pragma unroll
        for (int k = 0; k < 64; ++k) a2 += z1[k] * fw2[k * 32 + j];
        z2[j] = elu_f(a2);
    }
    __syncthreads();

    if (j < 10) {
        float a3 = fb3[j];
#pragma unroll
        for (int k = 0; k < 32; ++k) a3 += z2[k] * fw3[k * 10 + j];
        z3[j] = a3;
    }
    __syncthreads();

    if (j == 0) {
        float m = -1e30f;
        for (int i = 0; i < 10; ++i) m = fmaxf(m, z3[i]);
        float s = 0.f;
        for (int i = 0; i < 10; ++i) s += expf(z3[i] - m);
        lse = logf(s) + m;
    }
    __syncthreads();

    if (j < 10) out[(size_t)g * 10 + j] = z3[j] - lse;
}

// ---------------------------------------------------------------------------
extern "C" void kernel_launch(void* const* d_in, const int* in_sizes, int n_in,
                              void* d_out, int out_size, void* d_ws, size_t ws_size,
                              hipStream_t stream)
{
    const float* x       = (const float*)d_in[0];
    const int*   ei      = (const int*)  d_in[1];
    const int*   batch   = (const int*)  d_in[2];
    const float* w1_rel  = (const float*)d_in[3];
    const float* b1      = (const float*)d_in[4];
    const float* w1_root = (const float*)d_in[5];
    const float* w2_rel  = (const float*)d_in[6];
    const float* b2      = (const float*)d_in[7];
    const float* w2_root = (const float*)d_in[8];
    const float* w3_rel  = (const float*)d_in[9];
    const float* b3      = (const float*)d_in[10];
    const float* w3_root = (const float*)d_in[11];
    const float* fw1     = (const float*)d_in[12];
    const float* fb1     = (const float*)d_in[13];
    const float* fw2     = (const float*)d_in[14];
    const float* fb2     = (const float*)d_in[15];
    const float* fw3     = (const float*)d_in[16];
    const float* fb3     = (const float*)d_in[17];
    float* out = (float*)d_out;

    const int* src = ei;
    const int* dst = ei + N_EDGES_C;

    // workspace layout
    float*    agg = (float*)d_ws;                            // N*64 f32 (25.6MB)
    ushort_t* xb  = (ushort_t*)(agg + (size_t)N_NODES_C * 64);   // N*32 bf16
    ushort_t* h1  = xb + (size_t)N_NODES_C * 32;             // N*32 bf16
    ushort_t* h2  = h1 + (size_t)N_NODES_C * 32;             // N*64 bf16
    ushort_t* h3  = h2 + (size_t)N_NODES_C * 64;             // N*64 bf16
    float* sums = (float*)(h3 + (size_t)N_NODES_C * 64);     // 512*64 f
    float* cnts = sums + (size_t)N_GRAPHS_C * 64;            // 512 f
    int*   row_start = (int*)(cnts + N_GRAPHS_C);            // N+1 int
    int*   bcnt = row_start + N_NODES_C + 1;                 // NBUCK
    int*   bucket_base = bcnt + NBUCK;                       // NBUCK+1
    int*   cursor = bucket_base + NBUCK + 1;                 // NBUCK
    int*   ssrc = cursor + NBUCK;                            // nE int
    int*   ebuf = (int*)agg;  // aliased: CSR build done before gather writes agg

    // ---- input f32 -> bf16 (amortizes across 16 gathered reads/row) ----
    cvt_bf16<<<(N_NODES_C * 32 / 8 + 255) / 256, 256, 0, stream>>>(
        x, (uint_t*)xb, N_NODES_C * 32 / 8);

    // ---- bucketed CSR build ----
    hipMemsetAsync(bcnt, 0, NBUCK * sizeof(int), stream);
    bucket_count<<<(N_EDGES_C + CHUNK_A - 1) / CHUNK_A, 256, 0, stream>>>(
        dst, bcnt, N_EDGES_C);
    bucket_scan<<<1, 128, 0, stream>>>(bcnt, bucket_base, cursor, N_EDGES_C);
    bucket_pass<<<(N_EDGES_C + CHUNK_A - 1) / CHUNK_A, 256, 0, stream>>>(
        src, dst, cursor, ebuf, N_EDGES_C);
    bucket_build<<<NBUCK, 256, 0, stream>>>(bucket_base, ebuf, row_start, ssrc);

    // ---- layer 1: 32 -> 32, xb -> h1 ----
    gather_bf<32><<<(N_NODES_C + 63) / 64, 256, 0, stream>>>(
        xb, row_start, ssrc, agg, N_NODES_C);
    transform_bf<32, 32><<<(N_NODES_C + 127) / 128, 256, 0, stream>>>(
        agg, xb, w1_rel, b1, w1_root, h1, N_NODES_C);

    // ---- layer 2: 32 -> 64, h1 -> h2 ----
    gather_bf<32><<<(N_NODES_C + 63) / 64, 256, 0, stream>>>(
        h1, row_start, ssrc, agg, N_NODES_C);
    transform_bf<32, 64><<<(N_NODES_C + 63) / 64, 256, 0, stream>>>(
        agg, h1, w2_rel, b2, w2_root, h2, N_NODES_C);

    // ---- layer 3: 64 -> 64, h2 -> h3 ----
    gather_bf<64><<<(N_NODES_C + 31) / 32, 256, 0, stream>>>(
        h2, row_start, ssrc, agg, N_NODES_C);
    transform_bf<64, 64><<<(N_NODES_C + 63) / 64, 256, 0, stream>>>(
        agg, h2, w3_rel, b3, w3_root, h3, N_NODES_C);

    // ---- mean pool ----
    hipMemsetAsync(sums, 0, ((size_t)N_GRAPHS_C * 64 + N_GRAPHS_C) * sizeof(float), stream);
    pool_bf<<<(N_NODES_C + POOL_CHUNK - 1) / POOL_CHUNK, 256, 0, stream>>>(
        h3, batch, sums, cnts, N_NODES_C);

    // ---- MLP head + log_softmax ----
    mlp_kernel<<<N_GRAPHS_C, 64, 0, stream>>>(
        sums, cnts, fw1, fb1, fw2, fb2, fw3, fb3, out);
}